// Round 5
// baseline (2184.508 us; speedup 1.0000x reference)
//
#include <hip/hip_runtime.h>
#include <math.h>

#define NPTS 8192
#define LGAB2 (-13.0f)   // log2(1/8192)
#define NWAVE 16         // waves per block (1024 threads)
#define MARGIN 20.0f     // chunk skip margin vs M_est (exponent units, base 2)

typedef __attribute__((ext_vector_type(2))) float f2;
typedef __attribute__((ext_vector_type(4))) float f32x4;
typedef __attribute__((ext_vector_type(8))) short bf8;          // 8 bf16 (4 VGPR)
typedef __attribute__((ext_vector_type(8))) unsigned short us8;

__device__ __forceinline__ float fexp2(float x){
#if __has_builtin(__builtin_amdgcn_exp2f)
  return __builtin_amdgcn_exp2f(x);
#else
  return exp2f(x);
#endif
}
__device__ __forceinline__ f2 ffma2(f2 a, f2 b, f2 c){
  return __builtin_elementwise_fma(a, b, c);
}
__device__ __forceinline__ f2 fmax2(f2 a, f2 b){
  return __builtin_elementwise_max(a, b);
}
__device__ __forceinline__ f2 splat2(float v){ f2 r; r.x = v; r.y = v; return r; }

// bf16 round-to-nearest-even helpers + 3-way split (xh+xm+xl, residual 2^-27)
__device__ __forceinline__ unsigned short f2bf(float f){
  unsigned u = __builtin_bit_cast(unsigned, f);
  unsigned r = u + 0x7FFFu + ((u >> 16) & 1u);
  return (unsigned short)(r >> 16);
}
__device__ __forceinline__ float bf2f(unsigned short s){
  unsigned u = ((unsigned)s) << 16;
  return __builtin_bit_cast(float, u);
}
__device__ __forceinline__ void split3(float v, unsigned short& a,
                                       unsigned short& b, unsigned short& c){
  a = f2bf(v); float r = v - bf2f(a);
  b = f2bf(r); r -= bf2f(b);
  c = f2bf(r);
}

// sum over each 16-lane DPP row; lane 15 (mod 16) holds the row total
__device__ __forceinline__ float dpp_sum16(float x){
  int v = __builtin_bit_cast(int, x);
#define DPP_STEP(ctrl) { \
    int o = __builtin_amdgcn_update_dpp(0, v, ctrl, 0xF, 0xF, true); \
    float f = __builtin_bit_cast(float, v) + __builtin_bit_cast(float, o); \
    v = __builtin_bit_cast(int, f); }
  DPP_STEP(0x111)  // row_shr:1
  DPP_STEP(0x112)  // row_shr:2
  DPP_STEP(0x114)  // row_shr:4
  DPP_STEP(0x118)  // row_shr:8
#undef DPP_STEP
  return __builtin_bit_cast(float, v);
}

// ---------------- counting sort by 12-bit Morton key (16^3 cells) ------------
__global__ __launch_bounds__(1024) void ws_sort(
    const float* __restrict__ x, const float* __restrict__ y,
    unsigned* __restrict__ sidx)
{
  __shared__ unsigned hist[4096];
  __shared__ unsigned wtot[16];
  const float* p = blockIdx.x ? y : x;
  int tid = threadIdx.x;
  for (int i = tid; i < 4096; i += 1024) hist[i] = 0;
  __syncthreads();
  unsigned key[8];
  for (int t = 0; t < 8; ++t) {
    int i = tid + (t << 10);
    unsigned q0 = (unsigned)fminf(fmaxf(p[3*i  ] * 16.f, 0.f), 15.f);
    unsigned q1 = (unsigned)fminf(fmaxf(p[3*i+1] * 16.f, 0.f), 15.f);
    unsigned q2 = (unsigned)fminf(fmaxf(p[3*i+2] * 16.f, 0.f), 15.f);
    unsigned k = 0;
    #pragma unroll
    for (int bb = 0; bb < 4; ++bb)
      k |= (((q0 >> bb) & 1u) << (3*bb)) | (((q1 >> bb) & 1u) << (3*bb+1))
         | (((q2 >> bb) & 1u) << (3*bb+2));
    key[t] = k;
    atomicAdd(&hist[k], 1u);
  }
  __syncthreads();
  unsigned c0 = hist[4*tid], c1 = hist[4*tid+1], c2 = hist[4*tid+2], c3 = hist[4*tid+3];
  unsigned tsum = c0 + c1 + c2 + c3;
  int lane = tid & 63, wv = tid >> 6;
  unsigned inc = tsum;
  for (int d = 1; d < 64; d <<= 1) {
    unsigned o = __shfl_up(inc, d);
    if (lane >= d) inc += o;
  }
  if (lane == 63) wtot[wv] = inc;
  __syncthreads();
  unsigned woff = 0;
  for (int k = 0; k < wv; ++k) woff += wtot[k];
  unsigned base = woff + inc - tsum;
  hist[4*tid] = base; hist[4*tid+1] = base + c0;
  hist[4*tid+2] = base + c0 + c1; hist[4*tid+3] = base + c0 + c1 + c2;
  __syncthreads();
  for (int t = 0; t < 8; ++t) {
    int i = tid + (t << 10);
    unsigned pos = atomicAdd(&hist[key[t]], 1u);
    sidx[blockIdx.x * NPTS + pos] = i;
  }
}

// ---------------- B-pack static writer ----------------
// B-pack layout (shorts): [slot][ct(512)][g(4)*128][c(16)*8][j(8)]
// k-slot table p=g*8+j (A-side . B-side):
//  p0-2 xh_d.yh_d  p3-5 xm_d.yh_d  p6-8 xl_d.yh_d  p9-11 xh_d.ym_d
//  p12-14 xm_d.ym_d  p15-17 xh_d.yl_d  p18-20 1.h_split  p21-23 c_split.1
//  p24-31 zero. Any consistent A/B slot convention is valid (HW k-map is
//  symmetric between A and B); C layout col=lane&15,row=(lane>>4)*4+reg.
__device__ __forceinline__ void wbs(unsigned short* bp, int slot, int t,
    unsigned short h0, unsigned short h1, unsigned short h2,
    unsigned short m0, unsigned short m1, unsigned short m2,
    unsigned short l0, unsigned short l1, unsigned short l2)
{
  const unsigned short ONE = 0x3F80;
  size_t base = ((size_t)(slot*512 + (t >> 4))) * 512 + (size_t)(t & 15) * 8;
  us8 g0v = {h0,h1,h2,h0,h1,h2,h0,h1};
  us8 g1v = {h2,m0,m1,m2,m0,m1,m2,l0};
  us8 g2v = {l1,l2,0,0,0,ONE,ONE,ONE};   // h slots (j2..4) filled per phase
  us8 g3v = {0,0,0,0,0,0,0,0};
  *(us8*)(bp + base)        = g0v;
  *(us8*)(bp + base + 128)  = g1v;
  *(us8*)(bp + base + 256)  = g2v;
  *(us8*)(bp + base + 384)  = g3v;
}

__global__ __launch_bounds__(256) void ws_setup(
    const float* __restrict__ x, const float* __restrict__ y,
    const unsigned* __restrict__ sidx,
    float4* __restrict__ xp, float4* __restrict__ yp,
    unsigned short* __restrict__ bpA, unsigned short* __restrict__ bpB)
{
  int t = blockIdx.x * 256 + threadIdx.x;
  if (t >= NPTS) return;
  int ox = sidx[t], oy = sidx[NPTS + t];
  float x0 = x[3*ox], x1 = x[3*ox+1], x2 = x[3*ox+2];
  float xs = x0*x0 + x1*x1 + x2*x2;
  float y0 = y[3*oy], y1 = y[3*oy+1], y2 = y[3*oy+2];
  float ys = y0*y0 + y1*y1 + y2*y2;
  xp[t] = make_float4(x0,x1,x2,xs);
  yp[t] = make_float4(y0,y1,y2,ys);
  unsigned short a0,a1,a2,b0,b1,b2,c0,c1,c2;
  // x set -> columns of slots 1,2
  split3(x0,a0,b0,c0); split3(x1,a1,b1,c1); split3(x2,a2,b2,c2);
  wbs(bpA,1,t,a0,a1,a2,b0,b1,b2,c0,c1,c2);
  wbs(bpA,2,t,a0,a1,a2,b0,b1,b2,c0,c1,c2);
  wbs(bpB,1,t,a0,a1,a2,b0,b1,b2,c0,c1,c2);
  wbs(bpB,2,t,a0,a1,a2,b0,b1,b2,c0,c1,c2);
  // y set -> columns of slots 0,3
  split3(y0,a0,b0,c0); split3(y1,a1,b1,c1); split3(y2,a2,b2,c2);
  wbs(bpA,0,t,a0,a1,a2,b0,b1,b2,c0,c1,c2);
  wbs(bpA,3,t,a0,a1,a2,b0,b1,b2,c0,c1,c2);
  wbs(bpB,0,t,a0,a1,a2,b0,b1,b2,c0,c1,c2);
  wbs(bpB,3,t,a0,a1,a2,b0,b1,b2,c0,c1,c2);
}

// Per-16-pt cluster: bbox, centroid, and initial coarse pack (duals = 0).
__global__ __launch_bounds__(512) void ws_bbox(
    const float4* __restrict__ xp, const float4* __restrict__ yp,
    float4* __restrict__ bbox, float4* __restrict__ cent,
    float4* __restrict__ cc0, float inv0ce)
{
  int c = threadIdx.x;           // 0..511
  int set = blockIdx.x;
  const float4* pp = set ? yp : xp;
  float lx = 1e30f, ly = 1e30f, lz = 1e30f;
  float hxx = -1e30f, hyy = -1e30f, hzz = -1e30f;
  float sx = 0.f, sy = 0.f, sz = 0.f, hm = -3.0e38f;
  float hv[16];
  for (int k = 0; k < 16; ++k) {
    float4 v = pp[c*16+k];
    lx = fminf(lx, v.x); ly = fminf(ly, v.y); lz = fminf(lz, v.z);
    hxx = fmaxf(hxx, v.x); hyy = fmaxf(hyy, v.y); hzz = fmaxf(hzz, v.z);
    sx += v.x; sy += v.y; sz += v.z;
    float h = LGAB2 - 0.5f * v.w * inv0ce;
    hv[k] = h; hm = fmaxf(hm, h);
  }
  float se = 0.f;
  for (int k = 0; k < 16; ++k) se += fexp2(hv[k] - hm);
  float H = hm + log2f(se);
  bbox[(set*512+c)*2+0] = make_float4(lx, ly, lz, 0.f);
  bbox[(set*512+c)*2+1] = make_float4(hxx, hyy, hzz, 0.f);
  float cx = sx * 0.0625f, cy = sy * 0.0625f, cz = sz * 0.0625f;
  cent[set*512+c] = make_float4(cx, cy, cz, 0.f);
  int s1 = set ? 0 : 1, s2 = set ? 3 : 2;   // slots using this set as columns
  int p = c >> 1, sub = c & 1;
  float* a = (float*)(cc0 + (size_t)s1 * 512);
  a[p*8+sub] = cx; a[p*8+2+sub] = cy; a[p*8+4+sub] = cz; a[p*8+6+sub] = H;
  float* bq = (float*)(cc0 + (size_t)s2 * 512);
  bq[p*8+sub] = cx; bq[p*8+2+sub] = cy; bq[p*8+4+sub] = cz; bq[p*8+6+sub] = H;
}

// dmin^2 at 16-ROW-GROUP granularity.
__global__ __launch_bounds__(512) void ws_dmin(
    const float4* __restrict__ bbox, float* __restrict__ dmin)
{
  int b = blockIdx.x;
  int s = b >> 7, rb = b & 127;
  int c = threadIdx.x;
  int rset = (s == 0 || s == 2) ? 0 : 1;
  int cset = (s == 0 || s == 3) ? 1 : 0;
  float4 bl = bbox[(cset*512 + c)*2], bh = bbox[(cset*512 + c)*2+1];
  #pragma unroll
  for (int g = 0; g < 4; ++g) {
    float4 l = bbox[(rset*512 + 4*rb + g)*2];
    float4 h = bbox[(rset*512 + 4*rb + g)*2+1];
    float dx = fmaxf(0.f, fmaxf(l.x - bh.x, bl.x - h.x));
    float dy = fmaxf(0.f, fmaxf(l.y - bh.y, bl.y - h.y));
    float dz = fmaxf(0.f, fmaxf(l.z - bh.z, bl.z - h.z));
    dmin[(((size_t)s*512 + 4*rb + g) << 9) + c] = dx*dx + dy*dy + dz*dz;
  }
}

// One phase.
// mode 1: fine single pass via MFMA (R4) with R5 pipeline: 2 col-tiles per
//   iteration (8 independent MFMA chains), 2-deep B prefetch, packed f2
//   accumulate. u = ce*x.y + h_j + (hx - Mest) per 16x16 tile via
//   mfma_f32_16x16x32_bf16 (bf16 triple-split operands); VALU: exp2 + pk-add.
//   Skip at (16-col x 16-row) granularity from hmS/dmin.
// mode 2: coarse exact two-pass over 512 centroid-columns (eps > 0.15 regime).
// kind: 0 = assign (init), 1 = 0.5*(P+T) average, 2 = final (write Tfin)
__global__ __launch_bounds__(1024, 4) void ws_softmin(
    const float4* __restrict__ xp, const float4* __restrict__ yp,
    unsigned short* __restrict__ apack,
    const unsigned short* __restrict__ bpS, unsigned short* __restrict__ bpD,
    const float4* __restrict__ ccS, float4* __restrict__ ccD,
    const float* __restrict__ dmin, const float* __restrict__ hmS,
    float* __restrict__ hmD, float* __restrict__ Mw,
    const float4* __restrict__ cent,
    float* __restrict__ P, float* __restrict__ Tfin,
    float ce, float eps_ln2, float inv_next_ce, float rho_next, int kind, int mode)
{
  int b = blockIdx.x;
  int s = b >> 7;
  int rb = b & 127;
  int rowbase = rb << 6;
  int tid = threadIdx.x;
  int lane = tid & 63;
  int w = __builtin_amdgcn_readfirstlane(tid >> 6);

  int rset = (s == 0 || s == 2) ? 0 : 1;
  const float4* rp = rset ? yp : xp;
  float4 rv = rp[rowbase + lane];
  float hx = -0.5f * rv.w * ce;
  int row = rowbase + lane;

  __shared__ float lm[NWAVE][64];
  __shared__ float lss[NWAVE][64];
  float myMest = 0.f;

  if (mode == 2) {
    // ---- coarse exact two-pass: 512 centroid-cols, 32 per wave ----
    float a0 = rv.x * ce, a1 = rv.y * ce, a2 = rv.z * ce;
    f2 A0 = splat2(a0), A1 = splat2(a1), A2 = splat2(a2);
    const float4* pwc = ccS + (size_t)s*512 + (w << 5);
    f2 mA = {-3.0e38f, -3.0e38f}, mB = mA;
    #pragma unroll
    for (int pb = 0; pb < 16; pb += 2) {
      float4 P0 = pwc[2*pb+0], Q0 = pwc[2*pb+1];
      float4 P1 = pwc[2*pb+2], Q1 = pwc[2*pb+3];
      f2 X0={P0.x,P0.y}, Y0={P0.z,P0.w}, Z0={Q0.x,Q0.y}, W0={Q0.z,Q0.w};
      f2 X1={P1.x,P1.y}, Y1={P1.z,P1.w}, Z1={Q1.x,Q1.y}, W1={Q1.z,Q1.w};
      f2 t0 = ffma2(A2, Z0, W0); t0 = ffma2(A1, Y0, t0); t0 = ffma2(A0, X0, t0);
      f2 t1 = ffma2(A2, Z1, W1); t1 = ffma2(A1, Y1, t1); t1 = ffma2(A0, X1, t1);
      mA = fmax2(mA, t0); mB = fmax2(mB, t1);
    }
    f2 mAB = fmax2(mA, mB);
    float m = fmaxf(mAB.x, mAB.y);
    f2 M2 = {m, m};
    f2 sA = {0.f,0.f}, sB = {0.f,0.f};
    #pragma unroll
    for (int pb = 0; pb < 16; pb += 2) {
      float4 P0 = pwc[2*pb+0], Q0 = pwc[2*pb+1];
      float4 P1 = pwc[2*pb+2], Q1 = pwc[2*pb+3];
      f2 X0={P0.x,P0.y}, Y0={P0.z,P0.w}, Z0={Q0.x,Q0.y}, W0={Q0.z,Q0.w};
      f2 X1={P1.x,P1.y}, Y1={P1.z,P1.w}, Z1={Q1.x,Q1.y}, W1={Q1.z,Q1.w};
      f2 u0 = ffma2(A2, Z0, W0 - M2); u0 = ffma2(A1, Y0, u0); u0 = ffma2(A0, X0, u0);
      f2 u1 = ffma2(A2, Z1, W1 - M2); u1 = ffma2(A1, Y1, u1); u1 = ffma2(A0, X1, u1);
      f2 e0, e1;
      e0.x = fexp2(u0.x); e0.y = fexp2(u0.y);
      e1.x = fexp2(u1.x); e1.y = fexp2(u1.y);
      sA += e0; sB += e1;
    }
    f2 sAB = sA + sB;
    lm[w][lane] = m;
    lss[w][lane] = sAB.x + sAB.y;
  } else {
    // ---- fine single pass, MFMA, pipelined ----
    float MestL = Mw[(size_t)s * NPTS + rowbase + lane];
    myMest = MestL;
    // per-16-row-group MIN of Mest (exists-row skip semantics)
    float gmn = MestL;
    #pragma unroll
    for (int d = 8; d >= 1; d >>= 1) gmn = fminf(gmn, __shfl_xor(gmn, d));
    float thr0 = __shfl(gmn,  0) - MARGIN;
    float thr1 = __shfl(gmn, 16) - MARGIN;
    float thr2 = __shfl(gmn, 32) - MARGIN;
    float thr3 = __shfl(gmn, 48) - MARGIN;
    // masks: bit i of m[rt] -> ct = w + 16*i live for row-tile rt
    int il = lane & 31;
    int ctl = w + (il << 4);
    float hmv = hmS[s*512 + ctl];
    unsigned m0x, m1x, m2x, m3x;
    {
      float dm0 = dmin[(((size_t)s*512 + 4*rb + 0) << 9) + ctl];
      float dm1 = dmin[(((size_t)s*512 + 4*rb + 1) << 9) + ctl];
      float dm2 = dmin[(((size_t)s*512 + 4*rb + 2) << 9) + ctl];
      float dm3 = dmin[(((size_t)s*512 + 4*rb + 3) << 9) + ctl];
      bool lo = (lane < 32);
      m0x = (unsigned)__ballot(lo && (hmv - 0.5f*ce*dm0 > thr0));
      m1x = (unsigned)__ballot(lo && (hmv - 0.5f*ce*dm1 > thr1));
      m2x = (unsigned)__ballot(lo && (hmv - 0.5f*ce*dm2 > thr2));
      m3x = (unsigned)__ballot(lo && (hmv - 0.5f*ce*dm3 > thr3));
      if (m0x == 0u) m0x = 0xFFFFFFFFu;
      if (m1x == 0u) m1x = 0xFFFFFFFFu;
      if (m2x == 0u) m2x = 0xFFFFFFFFu;
      if (m3x == 0u) m3x = 0xFFFFFFFFu;
    }
    unsigned msk[4] = {m0x, m1x, m2x, m3x};
    unsigned any = m0x | m1x | m2x | m3x;
    // A fragments: 4 row-tiles
    const unsigned short* apb = apack + (((size_t)s * NPTS + rowbase) << 5);
    bf8 af[4];
    #pragma unroll
    for (int rt = 0; rt < 4; ++rt)
      af[rt] = *(const bf8*)(apb + (((rt*16) + (lane & 15)) << 5) + ((lane >> 4) << 3));
    f2 acc01[4], acc23[4];
    #pragma unroll
    for (int rt = 0; rt < 4; ++rt) { acc01[rt] = splat2(0.f); acc23[rt] = splat2(0.f); }
    const f32x4 kZero = {0.f,0.f,0.f,0.f};
    const unsigned short* bpb = bpS + (((size_t)s) << 18);
    int goff = ((lane >> 4) << 7) + ((lane & 15) << 3);
    unsigned rem = any;
    int i0 = __builtin_ctz(rem); rem &= rem - 1u;
    bf8 b0 = *(const bf8*)(bpb + (size_t)(w + (i0 << 4)) * 512 + goff);
    int i1 = -1; bf8 b1 = b0;
    if (rem) {
      i1 = __builtin_ctz(rem); rem &= rem - 1u;
      b1 = *(const bf8*)(bpb + (size_t)(w + (i1 << 4)) * 512 + goff);
    }
    while (i0 >= 0) {
      // 2-deep prefetch of the next pair (issued before this pair's compute)
      int i2 = -1, i3 = -1; bf8 b2 = b0, b3 = b0;
      if (rem) {
        i2 = __builtin_ctz(rem); rem &= rem - 1u;
        b2 = *(const bf8*)(bpb + (size_t)(w + (i2 << 4)) * 512 + goff);
      }
      if (rem) {
        i3 = __builtin_ctz(rem); rem &= rem - 1u;
        b3 = *(const bf8*)(bpb + (size_t)(w + (i3 << 4)) * 512 + goff);
      }
      // 8 independent MFMA chains
      f32x4 d0[4], d1[4];
      #pragma unroll
      for (int rt = 0; rt < 4; ++rt)
        if ((msk[rt] >> i0) & 1u)
          d0[rt] = __builtin_amdgcn_mfma_f32_16x16x32_bf16(af[rt], b0, kZero, 0, 0, 0);
      if (i1 >= 0) {
        #pragma unroll
        for (int rt = 0; rt < 4; ++rt)
          if ((msk[rt] >> i1) & 1u)
            d1[rt] = __builtin_amdgcn_mfma_f32_16x16x32_bf16(af[rt], b1, kZero, 0, 0, 0);
      }
      // exps + packed accumulate; per-acc order = ascending ic (bit-exact)
      #pragma unroll
      for (int rt = 0; rt < 4; ++rt) {
        if ((msk[rt] >> i0) & 1u) {
          f2 e01, e23;
          e01.x = fexp2(d0[rt].x); e01.y = fexp2(d0[rt].y);
          e23.x = fexp2(d0[rt].z); e23.y = fexp2(d0[rt].w);
          acc01[rt] += e01; acc23[rt] += e23;
        }
        if (i1 >= 0 && ((msk[rt] >> i1) & 1u)) {
          f2 e01, e23;
          e01.x = fexp2(d1[rt].x); e01.y = fexp2(d1[rt].y);
          e23.x = fexp2(d1[rt].z); e23.y = fexp2(d1[rt].w);
          acc01[rt] += e01; acc23[rt] += e23;
        }
      }
      i0 = i2; b0 = b2; i1 = i3; b1 = b3;
    }
    // reduce: sum over the 16 lanes of each group (cols) -> per-row totals
    #pragma unroll
    for (int rt = 0; rt < 4; ++rt) {
      float vq0 = dpp_sum16(acc01[rt].x);
      float vq1 = dpp_sum16(acc01[rt].y);
      float vq2 = dpp_sum16(acc23[rt].x);
      float vq3 = dpp_sum16(acc23[rt].y);
      if ((lane & 15) == 15) {
        int base = rt*16 + ((lane >> 4) << 2);
        lss[w][base + 0] = vq0;
        lss[w][base + 1] = vq1;
        lss[w][base + 2] = vq2;
        lss[w][base + 3] = vq3;
      }
    }
  }
  __syncthreads();

  if (tid < 64) {
    float L;
    if (mode == 1) {
      float S = 0.f;
      #pragma unroll
      for (int k = 0; k < NWAVE; ++k) S += lss[k][lane];
      S = fmaxf(S, 1e-30f);
      L = myMest + log2f(S);
    } else {
      float M = lm[0][lane];
      #pragma unroll
      for (int k = 1; k < NWAVE; ++k) M = fmaxf(M, lm[k][lane]);
      float S = 0.f;
      #pragma unroll
      for (int k = 0; k < NWAVE; ++k) S += lss[k][lane] * fexp2(lm[k][lane] - M);
      L = hx + M + log2f(S);
    }
    float T = -eps_ln2 * L;
    if (kind == 2) {
      Tfin[s * NPTS + row] = T;
    } else {
      float* Pr = P + s * NPTS;
      float Pn = (kind == 0) ? T : 0.5f * (Pr[row] + T);
      Pr[row] = Pn;
      int dst = (s == 0) ? 1 : ((s == 1) ? 0 : s);
      // h for dst-slot columns (3-way split into B-pack h slots)
      float hy = LGAB2 + (Pn - 0.5f * rv.w) * inv_next_ce;
      {
        unsigned short hh, hmm, hl;
        split3(hy, hh, hmm, hl);
        size_t hb = ((size_t)(dst*512 + (row >> 4))) * 512 + 256 + (size_t)(row & 15) * 8;
        bpD[hb + 2] = hh; bpD[hb + 3] = hmm; bpD[hb + 4] = hl;
      }
      // A-pack row record for own slot's next phase + Mw (= next Mest)
      float Mn = fmaf(L - LGAB2, rho_next, LGAB2);
      Mw[(size_t)s * NPTS + row] = Mn;
      {
        float cen = inv_next_ce;
        unsigned short a0h,a0m,a0l,a1h,a1m,a1l,a2h,a2m,a2l,ch,cm,cl;
        split3(rv.x * cen, a0h, a0m, a0l);
        split3(rv.y * cen, a1h, a1m, a1l);
        split3(rv.z * cen, a2h, a2m, a2l);
        float cr = (-0.5f * rv.w * cen) - Mn;
        split3(cr, ch, cm, cl);
        const unsigned short ONE = 0x3F80;
        us8 A0 = {a0h,a1h,a2h,a0m,a1m,a2m,a0l,a1l};
        us8 A1 = {a2l,a0h,a1h,a2h,a0m,a1m,a2m,a0h};
        us8 A2 = {a1h,a2h,ONE,ONE,ONE,ch,cm,cl};
        us8 A3 = {0,0,0,0,0,0,0,0};
        unsigned short* ap = apack + (((size_t)s * NPTS + row) << 5);
        *(us8*)(ap)      = A0;
        *(us8*)(ap + 8)  = A1;
        *(us8*)(ap + 16) = A2;
        *(us8*)(ap + 24) = A3;
      }
      // Skip-bound table: MUST be LGAB2 + Pn*ce (R14 errata: max(h_j) is NOT
      // a valid bound — the -0.5|y|^2 cancels against the x.y cross term).
      float hN = fmaf(Pn, inv_next_ce, LGAB2);
      #pragma unroll
      for (int d = 8; d >= 1; d >>= 1) hN = fmaxf(hN, __shfl_xor(hN, d));
      if ((lane & 15) == 0) hmD[dst*512 + 4*rb + (lane >> 4)] = hN;
      // coarse pack for next phase: cluster LSE of hy over 16-lane group
      float mh = hy;
      #pragma unroll
      for (int d = 8; d >= 1; d >>= 1) mh = fmaxf(mh, __shfl_xor(mh, d));
      float se = fexp2(hy - mh);
      #pragma unroll
      for (int d = 8; d >= 1; d >>= 1) se += __shfl_xor(se, d);
      float Hcs = mh + log2f(se);
      if ((lane & 15) == 0) {
        int gc = 4*rb + (lane >> 4);
        float4 cv = cent[rset*512 + gc];
        float* cc2 = (float*)(ccD + (size_t)dst * 512);
        int p2 = gc >> 1, sub2 = gc & 1;
        cc2[p2*8+sub2]   = cv.x;
        cc2[p2*8+2+sub2] = cv.y;
        cc2[p2*8+4+sub2] = cv.z;
        cc2[p2*8+6+sub2] = Hcs;
      }
    }
  }
}

// loss = mean(f_fin - p_fin) + mean(g_fin - q_fin), fp64 accumulation
__global__ __launch_bounds__(256) void ws_reduce(
    const float* __restrict__ Tfin, float* __restrict__ out)
{
  int tid = threadIdx.x;
  double acc = 0.0;
  for (int i = tid; i < NPTS; i += 256) {
    acc += (double)Tfin[0*NPTS+i] - (double)Tfin[2*NPTS+i]
         + (double)Tfin[1*NPTS+i] - (double)Tfin[3*NPTS+i];
  }
  __shared__ double sd[256];
  sd[tid] = acc; __syncthreads();
  for (int k = 128; k > 0; k >>= 1) {
    if (tid < k) sd[tid] += sd[tid + k];
    __syncthreads();
  }
  if (tid == 0) out[0] = (float)(sd[0] / (double)NPTS);
}

extern "C" void kernel_launch(void* const* d_in, const int* in_sizes, int n_in,
                              void* d_out, int out_size, void* d_ws, size_t ws_size,
                              hipStream_t stream)
{
  const float* x = (const float*)d_in[0];
  const float* y = (const float*)d_in[1];
  float* out = (float*)d_out;

  char* wsp = (char*)d_ws;
  float4*   xp   = (float4*)wsp;   wsp += (size_t)NPTS * 16;
  float4*   yp   = (float4*)wsp;   wsp += (size_t)NPTS * 16;
  unsigned short* apack = (unsigned short*)wsp; wsp += (size_t)4 * NPTS * 64;  // 2 MB
  unsigned short* bpA   = (unsigned short*)wsp; wsp += (size_t)4 * 512 * 1024; // 2 MB
  unsigned short* bpB   = (unsigned short*)wsp; wsp += (size_t)4 * 512 * 1024; // 2 MB
  float4*   ccA  = (float4*)wsp;   wsp += (size_t)4 * 512 * 16;
  float4*   ccB  = (float4*)wsp;   wsp += (size_t)4 * 512 * 16;
  float*    P    = (float*)wsp;    wsp += (size_t)4 * NPTS * 4;
  float*    Tfin = (float*)wsp;    wsp += (size_t)4 * NPTS * 4;
  unsigned* sidx = (unsigned*)wsp; wsp += (size_t)2 * NPTS * 4;
  float*    Mw   = (float*)wsp;    wsp += (size_t)4 * NPTS * 4;
  float*    hmA  = (float*)wsp;    wsp += (size_t)4 * 512 * 4;
  float*    hmB  = (float*)wsp;    wsp += (size_t)4 * 512 * 4;
  float4*   bbox = (float4*)wsp;   wsp += (size_t)2 * 512 * 2 * 16;
  float4*   cent = (float4*)wsp;   wsp += (size_t)2 * 512 * 16;
  float*    dmin = (float*)wsp;    wsp += (size_t)4 * 512 * 512 * 4;  // 4 MB

  // geomloss epsilon schedule (f64, exactly as Python builds it)
  double epss[64]; int n = 0;
  double e = 4.0;                       // DIAMETER**P
  const double r = 0.9 * 0.9;          // SCALING**P
  const double target = 0.01 * 0.01;   // BLUR**P
  while (e > target && n < 60) { epss[n++] = e; e *= r; }   // n == 51

  // Phase plan (identical to the 1128 µs baseline — no error headroom for
  // schedule approximations): eps > 0.15 -> coarse512 (mode 2) stride-3;
  // 0.15 >= eps > 0.0025 -> fine stride-2; eps <= 0.0025 -> fine dense.
  // Final extrapolation at eps_final, fine.
  float feps[80]; int md[80]; int NPH = 0;
  feps[NPH] = (float)epss[0]; md[NPH] = 2; NPH++;          // init (coarse)
  {
    int k = 0;
    while (k < n) {
      int coarse = (epss[k] > 0.15);
      feps[NPH] = (float)epss[k]; md[NPH] = coarse ? 2 : 1; NPH++;
      k += coarse ? 3 : ((epss[k] > 0.0025) ? 2 : 1);
    }
  }
  feps[NPH] = 1e-4f; md[NPH] = 1; NPH++;                   // final

  const double L2E  = 1.4426950408889634;
  const double LN2d = 0.6931471805599453;

  float inv0ce = (float)(L2E / (double)feps[0]);
  ws_sort<<<2, 1024, 0, stream>>>(x, y, sidx);
  ws_setup<<<(NPTS + 255) / 256, 256, 0, stream>>>(x, y, sidx, xp, yp, bpA, bpB);
  ws_bbox<<<2, 512, 0, stream>>>(xp, yp, bbox, cent, ccA, inv0ce);
  ws_dmin<<<512, 512, 0, stream>>>(bbox, dmin);

  for (int p = 0; p < NPH; ++p) {
    float epsf = feps[p];
    float ce = (float)(L2E / (double)epsf);
    float eps_ln2 = (float)((double)epsf * LN2d);
    float inv_next_ce = 0.f;
    float rho_next = 0.f;
    if (p < NPH - 1) {
      inv_next_ce = (float)(L2E / (double)feps[p+1]);
      rho_next = (float)((double)epsf / (double)feps[p+1]);
    }
    int kind = (p == 0) ? 0 : ((p == NPH - 1) ? 2 : 1);
    const unsigned short* bpS = (p & 1) ? bpB : bpA;
    unsigned short*       bpD_ = (p & 1) ? bpA : bpB;
    const float4* ccS = (p & 1) ? ccB : ccA;
    float4*       ccD = (p & 1) ? ccA : ccB;
    const float*  hmS = (p & 1) ? hmB : hmA;
    float*        hmD = (p & 1) ? hmA : hmB;
    ws_softmin<<<512, 1024, 0, stream>>>(xp, yp, apack, bpS, bpD_, ccS, ccD,
                                         dmin, hmS, hmD, Mw, cent, P, Tfin,
                                         ce, eps_ln2, inv_next_ce, rho_next,
                                         kind, md[p]);
  }

  ws_reduce<<<1, 256, 0, stream>>>(Tfin, out);
}

// Round 7
// 1041.220 us; speedup vs baseline: 2.0980x; 2.0980x over previous
//
#include <hip/hip_runtime.h>
#include <math.h>

#define NPTS 8192
#define LGAB2 (-13.0f)   // log2(1/8192)
#define NWAVE 16         // waves per block (1024 threads)
#define MARGIN 20.0f     // chunk skip margin vs M_est (exponent units, base 2)

typedef __attribute__((ext_vector_type(2))) float f2;
typedef __attribute__((ext_vector_type(4))) float f32x4;
typedef __attribute__((ext_vector_type(8))) short bf8;          // 8 bf16 (4 VGPR)
typedef __attribute__((ext_vector_type(8))) unsigned short us8;

__device__ __forceinline__ float fexp2(float x){
#if __has_builtin(__builtin_amdgcn_exp2f)
  return __builtin_amdgcn_exp2f(x);
#else
  return exp2f(x);
#endif
}
__device__ __forceinline__ f2 ffma2(f2 a, f2 b, f2 c){
  return __builtin_elementwise_fma(a, b, c);
}
__device__ __forceinline__ f2 fmax2(f2 a, f2 b){
  return __builtin_elementwise_max(a, b);
}
__device__ __forceinline__ f2 splat2(float v){ f2 r; r.x = v; r.y = v; return r; }

// bf16 round-to-nearest-even helpers + 3-way split (xh+xm+xl, residual 2^-27)
__device__ __forceinline__ unsigned short f2bf(float f){
  unsigned u = __builtin_bit_cast(unsigned, f);
  unsigned r = u + 0x7FFFu + ((u >> 16) & 1u);
  return (unsigned short)(r >> 16);
}
__device__ __forceinline__ float bf2f(unsigned short s){
  unsigned u = ((unsigned)s) << 16;
  return __builtin_bit_cast(float, u);
}
__device__ __forceinline__ void split3(float v, unsigned short& a,
                                       unsigned short& b, unsigned short& c){
  a = f2bf(v); float r = v - bf2f(a);
  b = f2bf(r); r -= bf2f(b);
  c = f2bf(r);
}

// sum over each 16-lane DPP row; lane 15 (mod 16) holds the row total
__device__ __forceinline__ float dpp_sum16(float x){
  int v = __builtin_bit_cast(int, x);
#define DPP_STEP(ctrl) { \
    int o = __builtin_amdgcn_update_dpp(0, v, ctrl, 0xF, 0xF, true); \
    float f = __builtin_bit_cast(float, v) + __builtin_bit_cast(float, o); \
    v = __builtin_bit_cast(int, f); }
  DPP_STEP(0x111)  // row_shr:1
  DPP_STEP(0x112)  // row_shr:2
  DPP_STEP(0x114)  // row_shr:4
  DPP_STEP(0x118)  // row_shr:8
#undef DPP_STEP
  return __builtin_bit_cast(float, v);
}

// ---------------- counting sort by 12-bit Morton key (16^3 cells) ------------
__global__ __launch_bounds__(1024) void ws_sort(
    const float* __restrict__ x, const float* __restrict__ y,
    unsigned* __restrict__ sidx)
{
  __shared__ unsigned hist[4096];
  __shared__ unsigned wtot[16];
  const float* p = blockIdx.x ? y : x;
  int tid = threadIdx.x;
  for (int i = tid; i < 4096; i += 1024) hist[i] = 0;
  __syncthreads();
  unsigned key[8];
  for (int t = 0; t < 8; ++t) {
    int i = tid + (t << 10);
    unsigned q0 = (unsigned)fminf(fmaxf(p[3*i  ] * 16.f, 0.f), 15.f);
    unsigned q1 = (unsigned)fminf(fmaxf(p[3*i+1] * 16.f, 0.f), 15.f);
    unsigned q2 = (unsigned)fminf(fmaxf(p[3*i+2] * 16.f, 0.f), 15.f);
    unsigned k = 0;
    #pragma unroll
    for (int bb = 0; bb < 4; ++bb)
      k |= (((q0 >> bb) & 1u) << (3*bb)) | (((q1 >> bb) & 1u) << (3*bb+1))
         | (((q2 >> bb) & 1u) << (3*bb+2));
    key[t] = k;
    atomicAdd(&hist[k], 1u);
  }
  __syncthreads();
  unsigned c0 = hist[4*tid], c1 = hist[4*tid+1], c2 = hist[4*tid+2], c3 = hist[4*tid+3];
  unsigned tsum = c0 + c1 + c2 + c3;
  int lane = tid & 63, wv = tid >> 6;
  unsigned inc = tsum;
  for (int d = 1; d < 64; d <<= 1) {
    unsigned o = __shfl_up(inc, d);
    if (lane >= d) inc += o;
  }
  if (lane == 63) wtot[wv] = inc;
  __syncthreads();
  unsigned woff = 0;
  for (int k = 0; k < wv; ++k) woff += wtot[k];
  unsigned base = woff + inc - tsum;
  hist[4*tid] = base; hist[4*tid+1] = base + c0;
  hist[4*tid+2] = base + c0 + c1; hist[4*tid+3] = base + c0 + c1 + c2;
  __syncthreads();
  for (int t = 0; t < 8; ++t) {
    int i = tid + (t << 10);
    unsigned pos = atomicAdd(&hist[key[t]], 1u);
    sidx[blockIdx.x * NPTS + pos] = i;
  }
}

// ---------------- B-pack static writer ----------------
// B-pack layout (shorts): [slot][ct(512)][g(4)*128][c(16)*8][j(8)]
// k-slot table p=g*8+j (A-side . B-side):
//  p0-2 xh_d.yh_d  p3-5 xm_d.yh_d  p6-8 xl_d.yh_d  p9-11 xh_d.ym_d
//  p12-14 xm_d.ym_d  p15-17 xh_d.yl_d  p18-20 1.h_split  p21-23 c_split.1
//  p24-31 zero. Any consistent A/B slot convention is valid (HW k-map is
//  symmetric between A and B); C layout col=lane&15,row=(lane>>4)*4+reg.
__device__ __forceinline__ void wbs(unsigned short* bp, int slot, int t,
    unsigned short h0, unsigned short h1, unsigned short h2,
    unsigned short m0, unsigned short m1, unsigned short m2,
    unsigned short l0, unsigned short l1, unsigned short l2)
{
  const unsigned short ONE = 0x3F80;
  size_t base = ((size_t)(slot*512 + (t >> 4))) * 512 + (size_t)(t & 15) * 8;
  us8 g0v = {h0,h1,h2,h0,h1,h2,h0,h1};
  us8 g1v = {h2,m0,m1,m2,m0,m1,m2,l0};
  us8 g2v = {l1,l2,0,0,0,ONE,ONE,ONE};   // h slots (j2..4) filled per phase
  us8 g3v = {0,0,0,0,0,0,0,0};
  *(us8*)(bp + base)        = g0v;
  *(us8*)(bp + base + 128)  = g1v;
  *(us8*)(bp + base + 256)  = g2v;
  *(us8*)(bp + base + 384)  = g3v;
}

__global__ __launch_bounds__(256) void ws_setup(
    const float* __restrict__ x, const float* __restrict__ y,
    const unsigned* __restrict__ sidx,
    float4* __restrict__ xp, float4* __restrict__ yp,
    unsigned short* __restrict__ bpA, unsigned short* __restrict__ bpB)
{
  int t = blockIdx.x * 256 + threadIdx.x;
  if (t >= NPTS) return;
  int ox = sidx[t], oy = sidx[NPTS + t];
  float x0 = x[3*ox], x1 = x[3*ox+1], x2 = x[3*ox+2];
  float xs = x0*x0 + x1*x1 + x2*x2;
  float y0 = y[3*oy], y1 = y[3*oy+1], y2 = y[3*oy+2];
  float ys = y0*y0 + y1*y1 + y2*y2;
  xp[t] = make_float4(x0,x1,x2,xs);
  yp[t] = make_float4(y0,y1,y2,ys);
  unsigned short a0,a1,a2,b0,b1,b2,c0,c1,c2;
  // x set -> columns of slots 1,2
  split3(x0,a0,b0,c0); split3(x1,a1,b1,c1); split3(x2,a2,b2,c2);
  wbs(bpA,1,t,a0,a1,a2,b0,b1,b2,c0,c1,c2);
  wbs(bpA,2,t,a0,a1,a2,b0,b1,b2,c0,c1,c2);
  wbs(bpB,1,t,a0,a1,a2,b0,b1,b2,c0,c1,c2);
  wbs(bpB,2,t,a0,a1,a2,b0,b1,b2,c0,c1,c2);
  // y set -> columns of slots 0,3
  split3(y0,a0,b0,c0); split3(y1,a1,b1,c1); split3(y2,a2,b2,c2);
  wbs(bpA,0,t,a0,a1,a2,b0,b1,b2,c0,c1,c2);
  wbs(bpA,3,t,a0,a1,a2,b0,b1,b2,c0,c1,c2);
  wbs(bpB,0,t,a0,a1,a2,b0,b1,b2,c0,c1,c2);
  wbs(bpB,3,t,a0,a1,a2,b0,b1,b2,c0,c1,c2);
}

// Per-16-pt cluster: bbox, centroid, and initial coarse pack (duals = 0).
__global__ __launch_bounds__(512) void ws_bbox(
    const float4* __restrict__ xp, const float4* __restrict__ yp,
    float4* __restrict__ bbox, float4* __restrict__ cent,
    float4* __restrict__ cc0, float inv0ce)
{
  int c = threadIdx.x;           // 0..511
  int set = blockIdx.x;
  const float4* pp = set ? yp : xp;
  float lx = 1e30f, ly = 1e30f, lz = 1e30f;
  float hxx = -1e30f, hyy = -1e30f, hzz = -1e30f;
  float sx = 0.f, sy = 0.f, sz = 0.f, hm = -3.0e38f;
  float hv[16];
  for (int k = 0; k < 16; ++k) {
    float4 v = pp[c*16+k];
    lx = fminf(lx, v.x); ly = fminf(ly, v.y); lz = fminf(lz, v.z);
    hxx = fmaxf(hxx, v.x); hyy = fmaxf(hyy, v.y); hzz = fmaxf(hzz, v.z);
    sx += v.x; sy += v.y; sz += v.z;
    float h = LGAB2 - 0.5f * v.w * inv0ce;
    hv[k] = h; hm = fmaxf(hm, h);
  }
  float se = 0.f;
  for (int k = 0; k < 16; ++k) se += fexp2(hv[k] - hm);
  float H = hm + log2f(se);
  bbox[(set*512+c)*2+0] = make_float4(lx, ly, lz, 0.f);
  bbox[(set*512+c)*2+1] = make_float4(hxx, hyy, hzz, 0.f);
  float cx = sx * 0.0625f, cy = sy * 0.0625f, cz = sz * 0.0625f;
  cent[set*512+c] = make_float4(cx, cy, cz, 0.f);
  int s1 = set ? 0 : 1, s2 = set ? 3 : 2;   // slots using this set as columns
  int p = c >> 1, sub = c & 1;
  float* a = (float*)(cc0 + (size_t)s1 * 512);
  a[p*8+sub] = cx; a[p*8+2+sub] = cy; a[p*8+4+sub] = cz; a[p*8+6+sub] = H;
  float* bq = (float*)(cc0 + (size_t)s2 * 512);
  bq[p*8+sub] = cx; bq[p*8+2+sub] = cy; bq[p*8+4+sub] = cz; bq[p*8+6+sub] = H;
}

// dmin^2 at 16-ROW-GROUP granularity.
__global__ __launch_bounds__(512) void ws_dmin(
    const float4* __restrict__ bbox, float* __restrict__ dmin)
{
  int b = blockIdx.x;
  int s = b >> 7, rb = b & 127;
  int c = threadIdx.x;
  int rset = (s == 0 || s == 2) ? 0 : 1;
  int cset = (s == 0 || s == 3) ? 1 : 0;
  float4 bl = bbox[(cset*512 + c)*2], bh = bbox[(cset*512 + c)*2+1];
  #pragma unroll
  for (int g = 0; g < 4; ++g) {
    float4 l = bbox[(rset*512 + 4*rb + g)*2];
    float4 h = bbox[(rset*512 + 4*rb + g)*2+1];
    float dx = fmaxf(0.f, fmaxf(l.x - bh.x, bl.x - h.x));
    float dy = fmaxf(0.f, fmaxf(l.y - bh.y, bl.y - h.y));
    float dz = fmaxf(0.f, fmaxf(l.z - bh.z, bl.z - h.z));
    dmin[(((size_t)s*512 + 4*rb + g) << 9) + c] = dx*dx + dy*dy + dz*dz;
  }
}

// One phase.
// mode 1: fine single pass via MFMA. R7: numerically BIT-IDENTICAL to R4
//   (same wave decomposition: 4 row-tiles x 32 cts (ct = w + i*16), same
//   per-rt masks, same union iteration order, same conditional accumulate
//   sequence), but stalls removed: MFMAs for all 4 rts issued UNCONDITIONALLY
//   into named regs D0-D3 (matrix pipe ~11% busy - free; skipped results
//   never touch accumulators), consumed ONE iteration later (named-reg E->D
//   pipeline, unconditional defs -> no scratch spill, R5 errata), plus 2-deep
//   B prefetch (load one iteration before its MFMA). R6 errata: union-mask /
//   regrouped accumulation shifted rounding by one output quantum - term set
//   and order must stay exactly R4's.
// mode 2: coarse exact two-pass over 512 centroid-columns (eps > 0.15 regime).
// kind: 0 = assign (init), 1 = 0.5*(P+T) average, 2 = final (write Tfin)
__global__ __launch_bounds__(1024, 4) void ws_softmin(
    const float4* __restrict__ xp, const float4* __restrict__ yp,
    unsigned short* __restrict__ apack,
    const unsigned short* __restrict__ bpS, unsigned short* __restrict__ bpD,
    const float4* __restrict__ ccS, float4* __restrict__ ccD,
    const float* __restrict__ dmin, const float* __restrict__ hmS,
    float* __restrict__ hmD, float* __restrict__ Mw,
    const float4* __restrict__ cent,
    float* __restrict__ P, float* __restrict__ Tfin,
    float ce, float eps_ln2, float inv_next_ce, float rho_next, int kind, int mode)
{
  int b = blockIdx.x;
  int s = b >> 7;
  int rb = b & 127;
  int rowbase = rb << 6;
  int tid = threadIdx.x;
  int lane = tid & 63;
  int w = __builtin_amdgcn_readfirstlane(tid >> 6);

  int rset = (s == 0 || s == 2) ? 0 : 1;
  const float4* rp = rset ? yp : xp;
  float4 rv = rp[rowbase + lane];
  float hx = -0.5f * rv.w * ce;
  int row = rowbase + lane;

  __shared__ float lm[NWAVE][64];
  __shared__ float lss[NWAVE][64];
  float myMest = 0.f;

  if (mode == 2) {
    // ---- coarse exact two-pass: 512 centroid-cols, 32 per wave ----
    float a0 = rv.x * ce, a1 = rv.y * ce, a2 = rv.z * ce;
    f2 A0 = splat2(a0), A1 = splat2(a1), A2 = splat2(a2);
    const float4* pwc = ccS + (size_t)s*512 + (w << 5);
    f2 mA = {-3.0e38f, -3.0e38f}, mB = mA;
    #pragma unroll
    for (int pb = 0; pb < 16; pb += 2) {
      float4 P0 = pwc[2*pb+0], Q0 = pwc[2*pb+1];
      float4 P1 = pwc[2*pb+2], Q1 = pwc[2*pb+3];
      f2 X0={P0.x,P0.y}, Y0={P0.z,P0.w}, Z0={Q0.x,Q0.y}, W0={Q0.z,Q0.w};
      f2 X1={P1.x,P1.y}, Y1={P1.z,P1.w}, Z1={Q1.x,Q1.y}, W1={Q1.z,Q1.w};
      f2 t0 = ffma2(A2, Z0, W0); t0 = ffma2(A1, Y0, t0); t0 = ffma2(A0, X0, t0);
      f2 t1 = ffma2(A2, Z1, W1); t1 = ffma2(A1, Y1, t1); t1 = ffma2(A0, X1, t1);
      mA = fmax2(mA, t0); mB = fmax2(mB, t1);
    }
    f2 mAB = fmax2(mA, mB);
    float m = fmaxf(mAB.x, mAB.y);
    f2 M2 = {m, m};
    f2 sA = {0.f,0.f}, sB = {0.f,0.f};
    #pragma unroll
    for (int pb = 0; pb < 16; pb += 2) {
      float4 P0 = pwc[2*pb+0], Q0 = pwc[2*pb+1];
      float4 P1 = pwc[2*pb+2], Q1 = pwc[2*pb+3];
      f2 X0={P0.x,P0.y}, Y0={P0.z,P0.w}, Z0={Q0.x,Q0.y}, W0={Q0.z,Q0.w};
      f2 X1={P1.x,P1.y}, Y1={P1.z,P1.w}, Z1={Q1.x,Q1.y}, W1={Q1.z,Q1.w};
      f2 u0 = ffma2(A2, Z0, W0 - M2); u0 = ffma2(A1, Y0, u0); u0 = ffma2(A0, X0, u0);
      f2 u1 = ffma2(A2, Z1, W1 - M2); u1 = ffma2(A1, Y1, u1); u1 = ffma2(A0, X1, u1);
      f2 e0, e1;
      e0.x = fexp2(u0.x); e0.y = fexp2(u0.y);
      e1.x = fexp2(u1.x); e1.y = fexp2(u1.y);
      sA += e0; sB += e1;
    }
    f2 sAB = sA + sB;
    lm[w][lane] = m;
    lss[w][lane] = sAB.x + sAB.y;
  } else {
    // ---- fine single pass, MFMA, pipelined (R4-exact numerics) ----
    float MestL = Mw[(size_t)s * NPTS + rowbase + lane];
    myMest = MestL;
    // per-16-row-group MIN of Mest (exists-row skip semantics)
    float gmn = MestL;
    #pragma unroll
    for (int d = 8; d >= 1; d >>= 1) gmn = fminf(gmn, __shfl_xor(gmn, d));
    float thr0 = __shfl(gmn,  0) - MARGIN;
    float thr1 = __shfl(gmn, 16) - MARGIN;
    float thr2 = __shfl(gmn, 32) - MARGIN;
    float thr3 = __shfl(gmn, 48) - MARGIN;
    // masks: bit i of m[rt] -> ct = w + 16*i live for row-tile rt
    int il = lane & 31;
    int ctl = w + (il << 4);
    float hmv = hmS[s*512 + ctl];
    unsigned m0x, m1x, m2x, m3x;
    {
      float dm0 = dmin[(((size_t)s*512 + 4*rb + 0) << 9) + ctl];
      float dm1 = dmin[(((size_t)s*512 + 4*rb + 1) << 9) + ctl];
      float dm2 = dmin[(((size_t)s*512 + 4*rb + 2) << 9) + ctl];
      float dm3 = dmin[(((size_t)s*512 + 4*rb + 3) << 9) + ctl];
      bool lo = (lane < 32);
      m0x = (unsigned)__ballot(lo && (hmv - 0.5f*ce*dm0 > thr0));
      m1x = (unsigned)__ballot(lo && (hmv - 0.5f*ce*dm1 > thr1));
      m2x = (unsigned)__ballot(lo && (hmv - 0.5f*ce*dm2 > thr2));
      m3x = (unsigned)__ballot(lo && (hmv - 0.5f*ce*dm3 > thr3));
      if (m0x == 0u) m0x = 0xFFFFFFFFu;
      if (m1x == 0u) m1x = 0xFFFFFFFFu;
      if (m2x == 0u) m2x = 0xFFFFFFFFu;
      if (m3x == 0u) m3x = 0xFFFFFFFFu;
    }
    unsigned any = m0x | m1x | m2x | m3x;
    // A fragments: 4 row-tiles (named)
    const unsigned short* apb = apack + (((size_t)s * NPTS + rowbase) << 5);
    int aoff = ((lane & 15) << 5) + ((lane >> 4) << 3);
    bf8 af0 = *(const bf8*)(apb + ((0*16) << 5) + aoff);
    bf8 af1 = *(const bf8*)(apb + ((1*16) << 5) + aoff);
    bf8 af2 = *(const bf8*)(apb + ((2*16) << 5) + aoff);
    bf8 af3 = *(const bf8*)(apb + ((3*16) << 5) + aoff);
    f2 acc01_0 = splat2(0.f), acc23_0 = splat2(0.f);
    f2 acc01_1 = splat2(0.f), acc23_1 = splat2(0.f);
    f2 acc01_2 = splat2(0.f), acc23_2 = splat2(0.f);
    f2 acc01_3 = splat2(0.f), acc23_3 = splat2(0.f);
    const f32x4 kZero = {0.f,0.f,0.f,0.f};
    const unsigned short* bpb = bpS + (((size_t)s) << 18);
    int goff = ((lane >> 4) << 7) + ((lane & 15) << 3);
    // pipeline prime: i0 = first live ct; inx = second (or dup of first)
    int cnt = __builtin_popcount(any);
    unsigned rem = any;
    int i0 = (int)__builtin_ctz(rem); rem &= rem - 1u;
    bf8 bcur = *(const bf8*)(bpb + (size_t)(w + (i0 << 4)) * 512 + goff);
    int inx = (int)__builtin_ctz(rem | 0x80000000u);
    if (inx == 31 && !(rem >> 31)) inx = i0;          // rem empty -> dup
    bf8 bnext = *(const bf8*)(bpb + (size_t)(w + (inx << 4)) * 512 + goff);
    rem &= rem - 1u;
    f32x4 D0 = __builtin_amdgcn_mfma_f32_16x16x32_bf16(af0, bcur, kZero, 0, 0, 0);
    f32x4 D1 = __builtin_amdgcn_mfma_f32_16x16x32_bf16(af1, bcur, kZero, 0, 0, 0);
    f32x4 D2 = __builtin_amdgcn_mfma_f32_16x16x32_bf16(af2, bcur, kZero, 0, 0, 0);
    f32x4 D3 = __builtin_amdgcn_mfma_f32_16x16x32_bf16(af3, bcur, kZero, 0, 0, 0);
    int icD = i0;
#define WS_CONSUME(Dr, m_, a01, a23) \
    if ((m_ >> icD) & 1u) { \
      f2 e01, e23; \
      e01.x = fexp2(Dr.x); e01.y = fexp2(Dr.y); \
      e23.x = fexp2(Dr.z); e23.y = fexp2(Dr.w); \
      a01 += e01; a23 += e23; }
    for (int k = 1; k < cnt; ++k) {
      int i2 = (int)__builtin_ctz(rem | 0x80000000u);
      // safe dummy when rem empty: reuse inx (valid address, value unused)
      int i2s = (rem == 0u) ? inx : i2;
      bf8 b2 = *(const bf8*)(bpb + (size_t)(w + (i2s << 4)) * 512 + goff);
      rem &= rem - 1u;
      // issue next MFMAs before consuming D (fills MFMA latency)
      f32x4 E0 = __builtin_amdgcn_mfma_f32_16x16x32_bf16(af0, bnext, kZero, 0, 0, 0);
      f32x4 E1 = __builtin_amdgcn_mfma_f32_16x16x32_bf16(af1, bnext, kZero, 0, 0, 0);
      f32x4 E2 = __builtin_amdgcn_mfma_f32_16x16x32_bf16(af2, bnext, kZero, 0, 0, 0);
      f32x4 E3 = __builtin_amdgcn_mfma_f32_16x16x32_bf16(af3, bnext, kZero, 0, 0, 0);
      // consume D (ct = icD) in R4's exact order: rt 0,1,2,3 ascending ct
      WS_CONSUME(D0, m0x, acc01_0, acc23_0)
      WS_CONSUME(D1, m1x, acc01_1, acc23_1)
      WS_CONSUME(D2, m2x, acc01_2, acc23_2)
      WS_CONSUME(D3, m3x, acc01_3, acc23_3)
      D0 = E0; D1 = E1; D2 = E2; D3 = E3;
      icD = inx;
      bnext = b2; inx = i2s;
    }
    // drain last ct
    WS_CONSUME(D0, m0x, acc01_0, acc23_0)
    WS_CONSUME(D1, m1x, acc01_1, acc23_1)
    WS_CONSUME(D2, m2x, acc01_2, acc23_2)
    WS_CONSUME(D3, m3x, acc01_3, acc23_3)
#undef WS_CONSUME
    // reduce: sum over the 16 lanes of each group (cols) -> per-row totals
    {
      float q0 = dpp_sum16(acc01_0.x), q1 = dpp_sum16(acc01_0.y);
      float q2 = dpp_sum16(acc23_0.x), q3 = dpp_sum16(acc23_0.y);
      if ((lane & 15) == 15) {
        int base = 0*16 + ((lane >> 4) << 2);
        lss[w][base+0] = q0; lss[w][base+1] = q1;
        lss[w][base+2] = q2; lss[w][base+3] = q3;
      }
      q0 = dpp_sum16(acc01_1.x); q1 = dpp_sum16(acc01_1.y);
      q2 = dpp_sum16(acc23_1.x); q3 = dpp_sum16(acc23_1.y);
      if ((lane & 15) == 15) {
        int base = 1*16 + ((lane >> 4) << 2);
        lss[w][base+0] = q0; lss[w][base+1] = q1;
        lss[w][base+2] = q2; lss[w][base+3] = q3;
      }
      q0 = dpp_sum16(acc01_2.x); q1 = dpp_sum16(acc01_2.y);
      q2 = dpp_sum16(acc23_2.x); q3 = dpp_sum16(acc23_2.y);
      if ((lane & 15) == 15) {
        int base = 2*16 + ((lane >> 4) << 2);
        lss[w][base+0] = q0; lss[w][base+1] = q1;
        lss[w][base+2] = q2; lss[w][base+3] = q3;
      }
      q0 = dpp_sum16(acc01_3.x); q1 = dpp_sum16(acc01_3.y);
      q2 = dpp_sum16(acc23_3.x); q3 = dpp_sum16(acc23_3.y);
      if ((lane & 15) == 15) {
        int base = 3*16 + ((lane >> 4) << 2);
        lss[w][base+0] = q0; lss[w][base+1] = q1;
        lss[w][base+2] = q2; lss[w][base+3] = q3;
      }
    }
  }
  __syncthreads();

  if (tid < 64) {
    float L;
    if (mode == 1) {
      float S = 0.f;
      #pragma unroll
      for (int k = 0; k < NWAVE; ++k) S += lss[k][lane];
      S = fmaxf(S, 1e-30f);
      L = myMest + log2f(S);
    } else {
      float M = lm[0][lane];
      #pragma unroll
      for (int k = 1; k < NWAVE; ++k) M = fmaxf(M, lm[k][lane]);
      float S = 0.f;
      #pragma unroll
      for (int k = 0; k < NWAVE; ++k) S += lss[k][lane] * fexp2(lm[k][lane] - M);
      L = hx + M + log2f(S);
    }
    float T = -eps_ln2 * L;
    if (kind == 2) {
      Tfin[s * NPTS + row] = T;
    } else {
      float* Pr = P + s * NPTS;
      float Pn = (kind == 0) ? T : 0.5f * (Pr[row] + T);
      Pr[row] = Pn;
      int dst = (s == 0) ? 1 : ((s == 1) ? 0 : s);
      // h for dst-slot columns (3-way split into B-pack h slots)
      float hy = LGAB2 + (Pn - 0.5f * rv.w) * inv_next_ce;
      {
        unsigned short hh, hmm, hl;
        split3(hy, hh, hmm, hl);
        size_t hb = ((size_t)(dst*512 + (row >> 4))) * 512 + 256 + (size_t)(row & 15) * 8;
        bpD[hb + 2] = hh; bpD[hb + 3] = hmm; bpD[hb + 4] = hl;
      }
      // A-pack row record for own slot's next phase + Mw (= next Mest)
      float Mn = fmaf(L - LGAB2, rho_next, LGAB2);
      Mw[(size_t)s * NPTS + row] = Mn;
      {
        float cen = inv_next_ce;
        unsigned short a0h,a0m,a0l,a1h,a1m,a1l,a2h,a2m,a2l,ch,cm,cl;
        split3(rv.x * cen, a0h, a0m, a0l);
        split3(rv.y * cen, a1h, a1m, a1l);
        split3(rv.z * cen, a2h, a2m, a2l);
        float cr = (-0.5f * rv.w * cen) - Mn;
        split3(cr, ch, cm, cl);
        const unsigned short ONE = 0x3F80;
        us8 A0 = {a0h,a1h,a2h,a0m,a1m,a2m,a0l,a1l};
        us8 A1 = {a2l,a0h,a1h,a2h,a0m,a1m,a2m,a0h};
        us8 A2 = {a1h,a2h,ONE,ONE,ONE,ch,cm,cl};
        us8 A3 = {0,0,0,0,0,0,0,0};
        unsigned short* ap = apack + (((size_t)s * NPTS + row) << 5);
        *(us8*)(ap)      = A0;
        *(us8*)(ap + 8)  = A1;
        *(us8*)(ap + 16) = A2;
        *(us8*)(ap + 24) = A3;
      }
      // Skip-bound table: MUST be LGAB2 + Pn*ce (R14 errata: max(h_j) is NOT
      // a valid bound — the -0.5|y|^2 cancels against the x.y cross term).
      float hN = fmaf(Pn, inv_next_ce, LGAB2);
      #pragma unroll
      for (int d = 8; d >= 1; d >>= 1) hN = fmaxf(hN, __shfl_xor(hN, d));
      if ((lane & 15) == 0) hmD[dst*512 + 4*rb + (lane >> 4)] = hN;
      // coarse pack for next phase: cluster LSE of hy over 16-lane group
      float mh = hy;
      #pragma unroll
      for (int d = 8; d >= 1; d >>= 1) mh = fmaxf(mh, __shfl_xor(mh, d));
      float se = fexp2(hy - mh);
      #pragma unroll
      for (int d = 8; d >= 1; d >>= 1) se += __shfl_xor(se, d);
      float Hcs = mh + log2f(se);
      if ((lane & 15) == 0) {
        int gc = 4*rb + (lane >> 4);
        float4 cv = cent[rset*512 + gc];
        float* cc2 = (float*)(ccD + (size_t)dst * 512);
        int p2 = gc >> 1, sub2 = gc & 1;
        cc2[p2*8+sub2]   = cv.x;
        cc2[p2*8+2+sub2] = cv.y;
        cc2[p2*8+4+sub2] = cv.z;
        cc2[p2*8+6+sub2] = Hcs;
      }
    }
  }
}

// loss = mean(f_fin - p_fin) + mean(g_fin - q_fin), fp64 accumulation
__global__ __launch_bounds__(256) void ws_reduce(
    const float* __restrict__ Tfin, float* __restrict__ out)
{
  int tid = threadIdx.x;
  double acc = 0.0;
  for (int i = tid; i < NPTS; i += 256) {
    acc += (double)Tfin[0*NPTS+i] - (double)Tfin[2*NPTS+i]
         + (double)Tfin[1*NPTS+i] - (double)Tfin[3*NPTS+i];
  }
  __shared__ double sd[256];
  sd[tid] = acc; __syncthreads();
  for (int k = 128; k > 0; k >>= 1) {
    if (tid < k) sd[tid] += sd[tid + k];
    __syncthreads();
  }
  if (tid == 0) out[0] = (float)(sd[0] / (double)NPTS);
}

extern "C" void kernel_launch(void* const* d_in, const int* in_sizes, int n_in,
                              void* d_out, int out_size, void* d_ws, size_t ws_size,
                              hipStream_t stream)
{
  const float* x = (const float*)d_in[0];
  const float* y = (const float*)d_in[1];
  float* out = (float*)d_out;

  char* wsp = (char*)d_ws;
  float4*   xp   = (float4*)wsp;   wsp += (size_t)NPTS * 16;
  float4*   yp   = (float4*)wsp;   wsp += (size_t)NPTS * 16;
  unsigned short* apack = (unsigned short*)wsp; wsp += (size_t)4 * NPTS * 64;  // 2 MB
  unsigned short* bpA   = (unsigned short*)wsp; wsp += (size_t)4 * 512 * 1024; // 2 MB
  unsigned short* bpB   = (unsigned short*)wsp; wsp += (size_t)4 * 512 * 1024; // 2 MB
  float4*   ccA  = (float4*)wsp;   wsp += (size_t)4 * 512 * 16;
  float4*   ccB  = (float4*)wsp;   wsp += (size_t)4 * 512 * 16;
  float*    P    = (float*)wsp;    wsp += (size_t)4 * NPTS * 4;
  float*    Tfin = (float*)wsp;    wsp += (size_t)4 * NPTS * 4;
  unsigned* sidx = (unsigned*)wsp; wsp += (size_t)2 * NPTS * 4;
  float*    Mw   = (float*)wsp;    wsp += (size_t)4 * NPTS * 4;
  float*    hmA  = (float*)wsp;    wsp += (size_t)4 * 512 * 4;
  float*    hmB  = (float*)wsp;    wsp += (size_t)4 * 512 * 4;
  float4*   bbox = (float4*)wsp;   wsp += (size_t)2 * 512 * 2 * 16;
  float4*   cent = (float4*)wsp;   wsp += (size_t)2 * 512 * 16;
  float*    dmin = (float*)wsp;    wsp += (size_t)4 * 512 * 512 * 4;  // 4 MB

  // geomloss epsilon schedule (f64, exactly as Python builds it)
  double epss[64]; int n = 0;
  double e = 4.0;                       // DIAMETER**P
  const double r = 0.9 * 0.9;          // SCALING**P
  const double target = 0.01 * 0.01;   // BLUR**P
  while (e > target && n < 60) { epss[n++] = e; e *= r; }   // n == 51

  // Phase plan (identical to the 1128 µs baseline — no error headroom for
  // schedule approximations): eps > 0.15 -> coarse512 (mode 2) stride-3;
  // 0.15 >= eps > 0.0025 -> fine stride-2; eps <= 0.0025 -> fine dense.
  // Final extrapolation at eps_final, fine.
  float feps[80]; int md[80]; int NPH = 0;
  feps[NPH] = (float)epss[0]; md[NPH] = 2; NPH++;          // init (coarse)
  {
    int k = 0;
    while (k < n) {
      int coarse = (epss[k] > 0.15);
      feps[NPH] = (float)epss[k]; md[NPH] = coarse ? 2 : 1; NPH++;
      k += coarse ? 3 : ((epss[k] > 0.0025) ? 2 : 1);
    }
  }
  feps[NPH] = 1e-4f; md[NPH] = 1; NPH++;                   // final

  const double L2E  = 1.4426950408889634;
  const double LN2d = 0.6931471805599453;

  float inv0ce = (float)(L2E / (double)feps[0]);
  ws_sort<<<2, 1024, 0, stream>>>(x, y, sidx);
  ws_setup<<<(NPTS + 255) / 256, 256, 0, stream>>>(x, y, sidx, xp, yp, bpA, bpB);
  ws_bbox<<<2, 512, 0, stream>>>(xp, yp, bbox, cent, ccA, inv0ce);
  ws_dmin<<<512, 512, 0, stream>>>(bbox, dmin);

  for (int p = 0; p < NPH; ++p) {
    float epsf = feps[p];
    float ce = (float)(L2E / (double)epsf);
    float eps_ln2 = (float)((double)epsf * LN2d);
    float inv_next_ce = 0.f;
    float rho_next = 0.f;
    if (p < NPH - 1) {
      inv_next_ce = (float)(L2E / (double)feps[p+1]);
      rho_next = (float)((double)epsf / (double)feps[p+1]);
    }
    int kind = (p == 0) ? 0 : ((p == NPH - 1) ? 2 : 1);
    const unsigned short* bpS = (p & 1) ? bpB : bpA;
    unsigned short*       bpD_ = (p & 1) ? bpA : bpB;
    const float4* ccS = (p & 1) ? ccB : ccA;
    float4*       ccD = (p & 1) ? ccA : ccB;
    const float*  hmS = (p & 1) ? hmB : hmA;
    float*        hmD = (p & 1) ? hmA : hmB;
    ws_softmin<<<512, 1024, 0, stream>>>(xp, yp, apack, bpS, bpD_, ccS, ccD,
                                         dmin, hmS, hmD, Mw, cent, P, Tfin,
                                         ce, eps_ln2, inv_next_ce, rho_next,
                                         kind, md[p]);
  }

  ws_reduce<<<1, 256, 0, stream>>>(Tfin, out);
}

// Round 8
// 925.757 us; speedup vs baseline: 2.3597x; 1.1247x over previous
//
#include <hip/hip_runtime.h>
#include <math.h>

#define NPTS 8192
#define LGAB2 (-13.0f)   // log2(1/8192)
#define NWAVE 16         // waves per block (1024 threads)
#define MARGIN 20.0f     // chunk skip margin vs M_est (exponent units, base 2)

typedef __attribute__((ext_vector_type(2))) float f2;
typedef __attribute__((ext_vector_type(4))) float f32x4;
typedef __attribute__((ext_vector_type(8))) short bf8;          // 8 bf16 (4 VGPR)
typedef __attribute__((ext_vector_type(8))) unsigned short us8;

__device__ __forceinline__ float fexp2(float x){
#if __has_builtin(__builtin_amdgcn_exp2f)
  return __builtin_amdgcn_exp2f(x);
#else
  return exp2f(x);
#endif
}
__device__ __forceinline__ f2 ffma2(f2 a, f2 b, f2 c){
  return __builtin_elementwise_fma(a, b, c);
}
__device__ __forceinline__ f2 fmax2(f2 a, f2 b){
  return __builtin_elementwise_max(a, b);
}
__device__ __forceinline__ f2 splat2(float v){ f2 r; r.x = v; r.y = v; return r; }

// bf16 round-to-nearest-even helpers + 3-way split (xh+xm+xl, residual 2^-27)
__device__ __forceinline__ unsigned short f2bf(float f){
  unsigned u = __builtin_bit_cast(unsigned, f);
  unsigned r = u + 0x7FFFu + ((u >> 16) & 1u);
  return (unsigned short)(r >> 16);
}
__device__ __forceinline__ float bf2f(unsigned short s){
  unsigned u = ((unsigned)s) << 16;
  return __builtin_bit_cast(float, u);
}
__device__ __forceinline__ void split3(float v, unsigned short& a,
                                       unsigned short& b, unsigned short& c){
  a = f2bf(v); float r = v - bf2f(a);
  b = f2bf(r); r -= bf2f(b);
  c = f2bf(r);
}

// sum over each 16-lane DPP row; lane 15 (mod 16) holds the row total
__device__ __forceinline__ float dpp_sum16(float x){
  int v = __builtin_bit_cast(int, x);
#define DPP_STEP(ctrl) { \
    int o = __builtin_amdgcn_update_dpp(0, v, ctrl, 0xF, 0xF, true); \
    float f = __builtin_bit_cast(float, v) + __builtin_bit_cast(float, o); \
    v = __builtin_bit_cast(int, f); }
  DPP_STEP(0x111)  // row_shr:1
  DPP_STEP(0x112)  // row_shr:2
  DPP_STEP(0x114)  // row_shr:4
  DPP_STEP(0x118)  // row_shr:8
#undef DPP_STEP
  return __builtin_bit_cast(float, v);
}

// ---------------- counting sort by 12-bit Morton key (16^3 cells) ------------
__global__ __launch_bounds__(1024) void ws_sort(
    const float* __restrict__ x, const float* __restrict__ y,
    unsigned* __restrict__ sidx)
{
  __shared__ unsigned hist[4096];
  __shared__ unsigned wtot[16];
  const float* p = blockIdx.x ? y : x;
  int tid = threadIdx.x;
  for (int i = tid; i < 4096; i += 1024) hist[i] = 0;
  __syncthreads();
  unsigned key[8];
  for (int t = 0; t < 8; ++t) {
    int i = tid + (t << 10);
    unsigned q0 = (unsigned)fminf(fmaxf(p[3*i  ] * 16.f, 0.f), 15.f);
    unsigned q1 = (unsigned)fminf(fmaxf(p[3*i+1] * 16.f, 0.f), 15.f);
    unsigned q2 = (unsigned)fminf(fmaxf(p[3*i+2] * 16.f, 0.f), 15.f);
    unsigned k = 0;
    #pragma unroll
    for (int bb = 0; bb < 4; ++bb)
      k |= (((q0 >> bb) & 1u) << (3*bb)) | (((q1 >> bb) & 1u) << (3*bb+1))
         | (((q2 >> bb) & 1u) << (3*bb+2));
    key[t] = k;
    atomicAdd(&hist[k], 1u);
  }
  __syncthreads();
  unsigned c0 = hist[4*tid], c1 = hist[4*tid+1], c2 = hist[4*tid+2], c3 = hist[4*tid+3];
  unsigned tsum = c0 + c1 + c2 + c3;
  int lane = tid & 63, wv = tid >> 6;
  unsigned inc = tsum;
  for (int d = 1; d < 64; d <<= 1) {
    unsigned o = __shfl_up(inc, d);
    if (lane >= d) inc += o;
  }
  if (lane == 63) wtot[wv] = inc;
  __syncthreads();
  unsigned woff = 0;
  for (int k = 0; k < wv; ++k) woff += wtot[k];
  unsigned base = woff + inc - tsum;
  hist[4*tid] = base; hist[4*tid+1] = base + c0;
  hist[4*tid+2] = base + c0 + c1; hist[4*tid+3] = base + c0 + c1 + c2;
  __syncthreads();
  for (int t = 0; t < 8; ++t) {
    int i = tid + (t << 10);
    unsigned pos = atomicAdd(&hist[key[t]], 1u);
    sidx[blockIdx.x * NPTS + pos] = i;
  }
}

// ---------------- B-pack static writer ----------------
// B-pack layout (shorts): [slot][ct(512)][g(4)*128][c(16)*8][j(8)]
// k-slot table p=g*8+j (A-side . B-side):
//  p0-2 xh_d.yh_d  p3-5 xm_d.yh_d  p6-8 xl_d.yh_d  p9-11 xh_d.ym_d
//  p12-14 xm_d.ym_d  p15-17 xh_d.yl_d  p18-20 1.h_split  p21-23 c_split.1
//  p24-31 zero. Any consistent A/B slot convention is valid (HW k-map is
//  symmetric between A and B); C layout col=lane&15,row=(lane>>4)*4+reg.
__device__ __forceinline__ void wbs(unsigned short* bp, int slot, int t,
    unsigned short h0, unsigned short h1, unsigned short h2,
    unsigned short m0, unsigned short m1, unsigned short m2,
    unsigned short l0, unsigned short l1, unsigned short l2)
{
  const unsigned short ONE = 0x3F80;
  size_t base = ((size_t)(slot*512 + (t >> 4))) * 512 + (size_t)(t & 15) * 8;
  us8 g0v = {h0,h1,h2,h0,h1,h2,h0,h1};
  us8 g1v = {h2,m0,m1,m2,m0,m1,m2,l0};
  us8 g2v = {l1,l2,0,0,0,ONE,ONE,ONE};   // h slots (j2..4) filled per phase
  us8 g3v = {0,0,0,0,0,0,0,0};
  *(us8*)(bp + base)        = g0v;
  *(us8*)(bp + base + 128)  = g1v;
  *(us8*)(bp + base + 256)  = g2v;
  *(us8*)(bp + base + 384)  = g3v;
}

__global__ __launch_bounds__(256) void ws_setup(
    const float* __restrict__ x, const float* __restrict__ y,
    const unsigned* __restrict__ sidx,
    float4* __restrict__ xp, float4* __restrict__ yp,
    unsigned short* __restrict__ bpA, unsigned short* __restrict__ bpB)
{
  int t = blockIdx.x * 256 + threadIdx.x;
  if (t >= NPTS) return;
  int ox = sidx[t], oy = sidx[NPTS + t];
  float x0 = x[3*ox], x1 = x[3*ox+1], x2 = x[3*ox+2];
  float xs = x0*x0 + x1*x1 + x2*x2;
  float y0 = y[3*oy], y1 = y[3*oy+1], y2 = y[3*oy+2];
  float ys = y0*y0 + y1*y1 + y2*y2;
  xp[t] = make_float4(x0,x1,x2,xs);
  yp[t] = make_float4(y0,y1,y2,ys);
  unsigned short a0,a1,a2,b0,b1,b2,c0,c1,c2;
  // x set -> columns of slots 1,2
  split3(x0,a0,b0,c0); split3(x1,a1,b1,c1); split3(x2,a2,b2,c2);
  wbs(bpA,1,t,a0,a1,a2,b0,b1,b2,c0,c1,c2);
  wbs(bpA,2,t,a0,a1,a2,b0,b1,b2,c0,c1,c2);
  wbs(bpB,1,t,a0,a1,a2,b0,b1,b2,c0,c1,c2);
  wbs(bpB,2,t,a0,a1,a2,b0,b1,b2,c0,c1,c2);
  // y set -> columns of slots 0,3
  split3(y0,a0,b0,c0); split3(y1,a1,b1,c1); split3(y2,a2,b2,c2);
  wbs(bpA,0,t,a0,a1,a2,b0,b1,b2,c0,c1,c2);
  wbs(bpA,3,t,a0,a1,a2,b0,b1,b2,c0,c1,c2);
  wbs(bpB,0,t,a0,a1,a2,b0,b1,b2,c0,c1,c2);
  wbs(bpB,3,t,a0,a1,a2,b0,b1,b2,c0,c1,c2);
}

// Per-16-pt cluster: bbox, centroid, and initial coarse pack (duals = 0).
__global__ __launch_bounds__(512) void ws_bbox(
    const float4* __restrict__ xp, const float4* __restrict__ yp,
    float4* __restrict__ bbox, float4* __restrict__ cent,
    float4* __restrict__ cc0, float inv0ce)
{
  int c = threadIdx.x;           // 0..511
  int set = blockIdx.x;
  const float4* pp = set ? yp : xp;
  float lx = 1e30f, ly = 1e30f, lz = 1e30f;
  float hxx = -1e30f, hyy = -1e30f, hzz = -1e30f;
  float sx = 0.f, sy = 0.f, sz = 0.f, hm = -3.0e38f;
  float hv[16];
  for (int k = 0; k < 16; ++k) {
    float4 v = pp[c*16+k];
    lx = fminf(lx, v.x); ly = fminf(ly, v.y); lz = fminf(lz, v.z);
    hxx = fmaxf(hxx, v.x); hyy = fmaxf(hyy, v.y); hzz = fmaxf(hzz, v.z);
    sx += v.x; sy += v.y; sz += v.z;
    float h = LGAB2 - 0.5f * v.w * inv0ce;
    hv[k] = h; hm = fmaxf(hm, h);
  }
  float se = 0.f;
  for (int k = 0; k < 16; ++k) se += fexp2(hv[k] - hm);
  float H = hm + log2f(se);
  bbox[(set*512+c)*2+0] = make_float4(lx, ly, lz, 0.f);
  bbox[(set*512+c)*2+1] = make_float4(hxx, hyy, hzz, 0.f);
  float cx = sx * 0.0625f, cy = sy * 0.0625f, cz = sz * 0.0625f;
  cent[set*512+c] = make_float4(cx, cy, cz, 0.f);
  int s1 = set ? 0 : 1, s2 = set ? 3 : 2;   // slots using this set as columns
  int p = c >> 1, sub = c & 1;
  float* a = (float*)(cc0 + (size_t)s1 * 512);
  a[p*8+sub] = cx; a[p*8+2+sub] = cy; a[p*8+4+sub] = cz; a[p*8+6+sub] = H;
  float* bq = (float*)(cc0 + (size_t)s2 * 512);
  bq[p*8+sub] = cx; bq[p*8+2+sub] = cy; bq[p*8+4+sub] = cz; bq[p*8+6+sub] = H;
}

// dmin^2 at 16-ROW-GROUP granularity.
__global__ __launch_bounds__(512) void ws_dmin(
    const float4* __restrict__ bbox, float* __restrict__ dmin)
{
  int b = blockIdx.x;
  int s = b >> 7, rb = b & 127;
  int c = threadIdx.x;
  int rset = (s == 0 || s == 2) ? 0 : 1;
  int cset = (s == 0 || s == 3) ? 1 : 0;
  float4 bl = bbox[(cset*512 + c)*2], bh = bbox[(cset*512 + c)*2+1];
  #pragma unroll
  for (int g = 0; g < 4; ++g) {
    float4 l = bbox[(rset*512 + 4*rb + g)*2];
    float4 h = bbox[(rset*512 + 4*rb + g)*2+1];
    float dx = fmaxf(0.f, fmaxf(l.x - bh.x, bl.x - h.x));
    float dy = fmaxf(0.f, fmaxf(l.y - bh.y, bl.y - h.y));
    float dz = fmaxf(0.f, fmaxf(l.z - bh.z, bl.z - h.z));
    dmin[(((size_t)s*512 + 4*rb + g) << 9) + c] = dx*dx + dy*dy + dz*dz;
  }
}

// One phase.
// mode 1: fine single pass via MFMA (R4-certified numerics). R8: dense-path
//   specialization — when ALL four rt masks are full (wave-uniform test; true
//   for the expensive mid-band full scans), run straight-line code: 4 batches
//   of {8 independent named B-loads, then 8 unconditional tile-consumes}.
//   Batched loads let the compiler emit counted vmcnt(7..0): one L2 stall per
//   8 cts instead of per ct (R4's 61% stall time). Term sequence = ct
//   ascending x rt 0..3 = exactly R4's full-mask execution -> bit-identical.
//   All other cases take R4's original loop VERBATIM. (R7 errata: interleaved
//   prefetch inside the consume loop gets serialized by vmcnt(0) before the
//   MFMA - issue loads in batches, never between issue and use of previous.)
// mode 2: coarse exact two-pass over 512 centroid-columns (eps > 0.15 regime).
// kind: 0 = assign (init), 1 = 0.5*(P+T) average, 2 = final (write Tfin)
__global__ __launch_bounds__(1024, 4) void ws_softmin(
    const float4* __restrict__ xp, const float4* __restrict__ yp,
    unsigned short* __restrict__ apack,
    const unsigned short* __restrict__ bpS, unsigned short* __restrict__ bpD,
    const float4* __restrict__ ccS, float4* __restrict__ ccD,
    const float* __restrict__ dmin, const float* __restrict__ hmS,
    float* __restrict__ hmD, float* __restrict__ Mw,
    const float4* __restrict__ cent,
    float* __restrict__ P, float* __restrict__ Tfin,
    float ce, float eps_ln2, float inv_next_ce, float rho_next, int kind, int mode)
{
  int b = blockIdx.x;
  int s = b >> 7;
  int rb = b & 127;
  int rowbase = rb << 6;
  int tid = threadIdx.x;
  int lane = tid & 63;
  int w = __builtin_amdgcn_readfirstlane(tid >> 6);

  int rset = (s == 0 || s == 2) ? 0 : 1;
  const float4* rp = rset ? yp : xp;
  float4 rv = rp[rowbase + lane];
  float hx = -0.5f * rv.w * ce;
  int row = rowbase + lane;

  __shared__ float lm[NWAVE][64];
  __shared__ float lss[NWAVE][64];
  float myMest = 0.f;

  if (mode == 2) {
    // ---- coarse exact two-pass: 512 centroid-cols, 32 per wave ----
    float a0 = rv.x * ce, a1 = rv.y * ce, a2 = rv.z * ce;
    f2 A0 = splat2(a0), A1 = splat2(a1), A2 = splat2(a2);
    const float4* pwc = ccS + (size_t)s*512 + (w << 5);
    f2 mA = {-3.0e38f, -3.0e38f}, mB = mA;
    #pragma unroll
    for (int pb = 0; pb < 16; pb += 2) {
      float4 P0 = pwc[2*pb+0], Q0 = pwc[2*pb+1];
      float4 P1 = pwc[2*pb+2], Q1 = pwc[2*pb+3];
      f2 X0={P0.x,P0.y}, Y0={P0.z,P0.w}, Z0={Q0.x,Q0.y}, W0={Q0.z,Q0.w};
      f2 X1={P1.x,P1.y}, Y1={P1.z,P1.w}, Z1={Q1.x,Q1.y}, W1={Q1.z,Q1.w};
      f2 t0 = ffma2(A2, Z0, W0); t0 = ffma2(A1, Y0, t0); t0 = ffma2(A0, X0, t0);
      f2 t1 = ffma2(A2, Z1, W1); t1 = ffma2(A1, Y1, t1); t1 = ffma2(A0, X1, t1);
      mA = fmax2(mA, t0); mB = fmax2(mB, t1);
    }
    f2 mAB = fmax2(mA, mB);
    float m = fmaxf(mAB.x, mAB.y);
    f2 M2 = {m, m};
    f2 sA = {0.f,0.f}, sB = {0.f,0.f};
    #pragma unroll
    for (int pb = 0; pb < 16; pb += 2) {
      float4 P0 = pwc[2*pb+0], Q0 = pwc[2*pb+1];
      float4 P1 = pwc[2*pb+2], Q1 = pwc[2*pb+3];
      f2 X0={P0.x,P0.y}, Y0={P0.z,P0.w}, Z0={Q0.x,Q0.y}, W0={Q0.z,Q0.w};
      f2 X1={P1.x,P1.y}, Y1={P1.z,P1.w}, Z1={Q1.x,Q1.y}, W1={Q1.z,Q1.w};
      f2 u0 = ffma2(A2, Z0, W0 - M2); u0 = ffma2(A1, Y0, u0); u0 = ffma2(A0, X0, u0);
      f2 u1 = ffma2(A2, Z1, W1 - M2); u1 = ffma2(A1, Y1, u1); u1 = ffma2(A0, X1, u1);
      f2 e0, e1;
      e0.x = fexp2(u0.x); e0.y = fexp2(u0.y);
      e1.x = fexp2(u1.x); e1.y = fexp2(u1.y);
      sA += e0; sB += e1;
    }
    f2 sAB = sA + sB;
    lm[w][lane] = m;
    lss[w][lane] = sAB.x + sAB.y;
  } else {
    // ---- fine single pass, MFMA ----
    float MestL = Mw[(size_t)s * NPTS + rowbase + lane];
    myMest = MestL;
    // per-16-row-group MIN of Mest (exists-row skip semantics)
    float gmn = MestL;
    #pragma unroll
    for (int d = 8; d >= 1; d >>= 1) gmn = fminf(gmn, __shfl_xor(gmn, d));
    float thr0 = __shfl(gmn,  0) - MARGIN;
    float thr1 = __shfl(gmn, 16) - MARGIN;
    float thr2 = __shfl(gmn, 32) - MARGIN;
    float thr3 = __shfl(gmn, 48) - MARGIN;
    // masks: bit i of m[rt] -> ct = w + 16*i live for row-tile rt
    int il = lane & 31;
    int ctl = w + (il << 4);
    float hmv = hmS[s*512 + ctl];
    unsigned m0x, m1x, m2x, m3x;
    {
      float dm0 = dmin[(((size_t)s*512 + 4*rb + 0) << 9) + ctl];
      float dm1 = dmin[(((size_t)s*512 + 4*rb + 1) << 9) + ctl];
      float dm2 = dmin[(((size_t)s*512 + 4*rb + 2) << 9) + ctl];
      float dm3 = dmin[(((size_t)s*512 + 4*rb + 3) << 9) + ctl];
      bool lo = (lane < 32);
      m0x = (unsigned)__ballot(lo && (hmv - 0.5f*ce*dm0 > thr0));
      m1x = (unsigned)__ballot(lo && (hmv - 0.5f*ce*dm1 > thr1));
      m2x = (unsigned)__ballot(lo && (hmv - 0.5f*ce*dm2 > thr2));
      m3x = (unsigned)__ballot(lo && (hmv - 0.5f*ce*dm3 > thr3));
      if (m0x == 0u) m0x = 0xFFFFFFFFu;
      if (m1x == 0u) m1x = 0xFFFFFFFFu;
      if (m2x == 0u) m2x = 0xFFFFFFFFu;
      if (m3x == 0u) m3x = 0xFFFFFFFFu;
    }
    unsigned msk[4] = {m0x, m1x, m2x, m3x};
    unsigned any = m0x | m1x | m2x | m3x;
    unsigned allm = m0x & m1x & m2x & m3x;
    // A fragments: 4 row-tiles
    const unsigned short* apb = apack + (((size_t)s * NPTS + rowbase) << 5);
    bf8 af[4];
    #pragma unroll
    for (int rt = 0; rt < 4; ++rt)
      af[rt] = *(const bf8*)(apb + (((rt*16) + (lane & 15)) << 5) + ((lane >> 4) << 3));
    f32x4 acc[4];
    #pragma unroll
    for (int rt = 0; rt < 4; ++rt) acc[rt] = (f32x4){0.f,0.f,0.f,0.f};
    const f32x4 kZero = {0.f,0.f,0.f,0.f};
    const unsigned short* bpb = bpS + (((size_t)s) << 18);
    int goff = ((lane >> 4) << 7) + ((lane & 15) << 3);
    if (allm == 0xFFFFFFFFu) {
      // ---- dense path: all masks full -> straight-line, batched loads ----
#define WS_TILE(BK) { \
      f32x4 d0 = __builtin_amdgcn_mfma_f32_16x16x32_bf16(af[0], BK, kZero, 0, 0, 0); \
      f32x4 d1 = __builtin_amdgcn_mfma_f32_16x16x32_bf16(af[1], BK, kZero, 0, 0, 0); \
      f32x4 d2 = __builtin_amdgcn_mfma_f32_16x16x32_bf16(af[2], BK, kZero, 0, 0, 0); \
      f32x4 d3 = __builtin_amdgcn_mfma_f32_16x16x32_bf16(af[3], BK, kZero, 0, 0, 0); \
      f32x4 e0; \
      e0.x = fexp2(d0.x); e0.y = fexp2(d0.y); e0.z = fexp2(d0.z); e0.w = fexp2(d0.w); \
      acc[0] += e0; \
      f32x4 e1; \
      e1.x = fexp2(d1.x); e1.y = fexp2(d1.y); e1.z = fexp2(d1.z); e1.w = fexp2(d1.w); \
      acc[1] += e1; \
      f32x4 e2; \
      e2.x = fexp2(d2.x); e2.y = fexp2(d2.y); e2.z = fexp2(d2.z); e2.w = fexp2(d2.w); \
      acc[2] += e2; \
      f32x4 e3; \
      e3.x = fexp2(d3.x); e3.y = fexp2(d3.y); e3.z = fexp2(d3.z); e3.w = fexp2(d3.w); \
      acc[3] += e3; }
      #pragma unroll 1
      for (int bb = 0; bb < 4; ++bb) {
        const unsigned short* bq = bpb + (size_t)(w + ((bb*8) << 4)) * 512 + goff;
        // 8 independent loads issued back-to-back (16KB stride per ct)
        bf8 s0 = *(const bf8*)(bq);
        bf8 s1 = *(const bf8*)(bq + 1*8192);
        bf8 s2 = *(const bf8*)(bq + 2*8192);
        bf8 s3 = *(const bf8*)(bq + 3*8192);
        bf8 s4 = *(const bf8*)(bq + 4*8192);
        bf8 s5 = *(const bf8*)(bq + 5*8192);
        bf8 s6 = *(const bf8*)(bq + 6*8192);
        bf8 s7 = *(const bf8*)(bq + 7*8192);
        WS_TILE(s0) WS_TILE(s1) WS_TILE(s2) WS_TILE(s3)
        WS_TILE(s4) WS_TILE(s5) WS_TILE(s6) WS_TILE(s7)
      }
#undef WS_TILE
    } else {
      // ---- sparse path: R4's loop verbatim ----
      unsigned rem = any;
      int ic = __builtin_ctz(rem); rem &= rem - 1u;
      bf8 bc = *(const bf8*)(bpb + (size_t)(w + (ic << 4)) * 512 + goff);
      for (;;) {
        int in = -1; bf8 bn;
        if (rem) {
          in = __builtin_ctz(rem); rem &= rem - 1u;
          bn = *(const bf8*)(bpb + (size_t)(w + (in << 4)) * 512 + goff);
        }
        #pragma unroll
        for (int rt = 0; rt < 4; ++rt) {
          if ((msk[rt] >> ic) & 1u) {
            f32x4 d = __builtin_amdgcn_mfma_f32_16x16x32_bf16(af[rt], bc, kZero, 0, 0, 0);
            f32x4 e;
            e.x = fexp2(d.x); e.y = fexp2(d.y); e.z = fexp2(d.z); e.w = fexp2(d.w);
            acc[rt] += e;
          }
        }
        if (in < 0) break;
        ic = in; bc = bn;
      }
    }
    // reduce: sum over the 16 lanes of each group (cols) -> per-row totals
    #pragma unroll
    for (int rt = 0; rt < 4; ++rt) {
      #pragma unroll
      for (int q = 0; q < 4; ++q) {
        float v = dpp_sum16(acc[rt][q]);
        if ((lane & 15) == 15)
          lss[w][rt*16 + ((lane >> 4) << 2) + q] = v;
      }
    }
  }
  __syncthreads();

  if (tid < 64) {
    float L;
    if (mode == 1) {
      float S = 0.f;
      #pragma unroll
      for (int k = 0; k < NWAVE; ++k) S += lss[k][lane];
      S = fmaxf(S, 1e-30f);
      L = myMest + log2f(S);
    } else {
      float M = lm[0][lane];
      #pragma unroll
      for (int k = 1; k < NWAVE; ++k) M = fmaxf(M, lm[k][lane]);
      float S = 0.f;
      #pragma unroll
      for (int k = 0; k < NWAVE; ++k) S += lss[k][lane] * fexp2(lm[k][lane] - M);
      L = hx + M + log2f(S);
    }
    float T = -eps_ln2 * L;
    if (kind == 2) {
      Tfin[s * NPTS + row] = T;
    } else {
      float* Pr = P + s * NPTS;
      float Pn = (kind == 0) ? T : 0.5f * (Pr[row] + T);
      Pr[row] = Pn;
      int dst = (s == 0) ? 1 : ((s == 1) ? 0 : s);
      // h for dst-slot columns (3-way split into B-pack h slots)
      float hy = LGAB2 + (Pn - 0.5f * rv.w) * inv_next_ce;
      {
        unsigned short hh, hmm, hl;
        split3(hy, hh, hmm, hl);
        size_t hb = ((size_t)(dst*512 + (row >> 4))) * 512 + 256 + (size_t)(row & 15) * 8;
        bpD[hb + 2] = hh; bpD[hb + 3] = hmm; bpD[hb + 4] = hl;
      }
      // A-pack row record for own slot's next phase + Mw (= next Mest)
      float Mn = fmaf(L - LGAB2, rho_next, LGAB2);
      Mw[(size_t)s * NPTS + row] = Mn;
      {
        float cen = inv_next_ce;
        unsigned short a0h,a0m,a0l,a1h,a1m,a1l,a2h,a2m,a2l,ch,cm,cl;
        split3(rv.x * cen, a0h, a0m, a0l);
        split3(rv.y * cen, a1h, a1m, a1l);
        split3(rv.z * cen, a2h, a2m, a2l);
        float cr = (-0.5f * rv.w * cen) - Mn;
        split3(cr, ch, cm, cl);
        const unsigned short ONE = 0x3F80;
        us8 A0 = {a0h,a1h,a2h,a0m,a1m,a2m,a0l,a1l};
        us8 A1 = {a2l,a0h,a1h,a2h,a0m,a1m,a2m,a0h};
        us8 A2 = {a1h,a2h,ONE,ONE,ONE,ch,cm,cl};
        us8 A3 = {0,0,0,0,0,0,0,0};
        unsigned short* ap = apack + (((size_t)s * NPTS + row) << 5);
        *(us8*)(ap)      = A0;
        *(us8*)(ap + 8)  = A1;
        *(us8*)(ap + 16) = A2;
        *(us8*)(ap + 24) = A3;
      }
      // Skip-bound table: MUST be LGAB2 + Pn*ce (R14 errata: max(h_j) is NOT
      // a valid bound — the -0.5|y|^2 cancels against the x.y cross term).
      float hN = fmaf(Pn, inv_next_ce, LGAB2);
      #pragma unroll
      for (int d = 8; d >= 1; d >>= 1) hN = fmaxf(hN, __shfl_xor(hN, d));
      if ((lane & 15) == 0) hmD[dst*512 + 4*rb + (lane >> 4)] = hN;
      // coarse pack for next phase: cluster LSE of hy over 16-lane group
      float mh = hy;
      #pragma unroll
      for (int d = 8; d >= 1; d >>= 1) mh = fmaxf(mh, __shfl_xor(mh, d));
      float se = fexp2(hy - mh);
      #pragma unroll
      for (int d = 8; d >= 1; d >>= 1) se += __shfl_xor(se, d);
      float Hcs = mh + log2f(se);
      if ((lane & 15) == 0) {
        int gc = 4*rb + (lane >> 4);
        float4 cv = cent[rset*512 + gc];
        float* cc2 = (float*)(ccD + (size_t)dst * 512);
        int p2 = gc >> 1, sub2 = gc & 1;
        cc2[p2*8+sub2]   = cv.x;
        cc2[p2*8+2+sub2] = cv.y;
        cc2[p2*8+4+sub2] = cv.z;
        cc2[p2*8+6+sub2] = Hcs;
      }
    }
  }
}

// loss = mean(f_fin - p_fin) + mean(g_fin - q_fin), fp64 accumulation
__global__ __launch_bounds__(256) void ws_reduce(
    const float* __restrict__ Tfin, float* __restrict__ out)
{
  int tid = threadIdx.x;
  double acc = 0.0;
  for (int i = tid; i < NPTS; i += 256) {
    acc += (double)Tfin[0*NPTS+i] - (double)Tfin[2*NPTS+i]
         + (double)Tfin[1*NPTS+i] - (double)Tfin[3*NPTS+i];
  }
  __shared__ double sd[256];
  sd[tid] = acc; __syncthreads();
  for (int k = 128; k > 0; k >>= 1) {
    if (tid < k) sd[tid] += sd[tid + k];
    __syncthreads();
  }
  if (tid == 0) out[0] = (float)(sd[0] / (double)NPTS);
}

extern "C" void kernel_launch(void* const* d_in, const int* in_sizes, int n_in,
                              void* d_out, int out_size, void* d_ws, size_t ws_size,
                              hipStream_t stream)
{
  const float* x = (const float*)d_in[0];
  const float* y = (const float*)d_in[1];
  float* out = (float*)d_out;

  char* wsp = (char*)d_ws;
  float4*   xp   = (float4*)wsp;   wsp += (size_t)NPTS * 16;
  float4*   yp   = (float4*)wsp;   wsp += (size_t)NPTS * 16;
  unsigned short* apack = (unsigned short*)wsp; wsp += (size_t)4 * NPTS * 64;  // 2 MB
  unsigned short* bpA   = (unsigned short*)wsp; wsp += (size_t)4 * 512 * 1024; // 2 MB
  unsigned short* bpB   = (unsigned short*)wsp; wsp += (size_t)4 * 512 * 1024; // 2 MB
  float4*   ccA  = (float4*)wsp;   wsp += (size_t)4 * 512 * 16;
  float4*   ccB  = (float4*)wsp;   wsp += (size_t)4 * 512 * 16;
  float*    P    = (float*)wsp;    wsp += (size_t)4 * NPTS * 4;
  float*    Tfin = (float*)wsp;    wsp += (size_t)4 * NPTS * 4;
  unsigned* sidx = (unsigned*)wsp; wsp += (size_t)2 * NPTS * 4;
  float*    Mw   = (float*)wsp;    wsp += (size_t)4 * NPTS * 4;
  float*    hmA  = (float*)wsp;    wsp += (size_t)4 * 512 * 4;
  float*    hmB  = (float*)wsp;    wsp += (size_t)4 * 512 * 4;
  float4*   bbox = (float4*)wsp;   wsp += (size_t)2 * 512 * 2 * 16;
  float4*   cent = (float4*)wsp;   wsp += (size_t)2 * 512 * 16;
  float*    dmin = (float*)wsp;    wsp += (size_t)4 * 512 * 512 * 4;  // 4 MB

  // geomloss epsilon schedule (f64, exactly as Python builds it)
  double epss[64]; int n = 0;
  double e = 4.0;                       // DIAMETER**P
  const double r = 0.9 * 0.9;          // SCALING**P
  const double target = 0.01 * 0.01;   // BLUR**P
  while (e > target && n < 60) { epss[n++] = e; e *= r; }   // n == 51

  // Phase plan (identical to the 1128 µs baseline — no error headroom for
  // schedule approximations): eps > 0.15 -> coarse512 (mode 2) stride-3;
  // 0.15 >= eps > 0.0025 -> fine stride-2; eps <= 0.0025 -> fine dense.
  // Final extrapolation at eps_final, fine.
  float feps[80]; int md[80]; int NPH = 0;
  feps[NPH] = (float)epss[0]; md[NPH] = 2; NPH++;          // init (coarse)
  {
    int k = 0;
    while (k < n) {
      int coarse = (epss[k] > 0.15);
      feps[NPH] = (float)epss[k]; md[NPH] = coarse ? 2 : 1; NPH++;
      k += coarse ? 3 : ((epss[k] > 0.0025) ? 2 : 1);
    }
  }
  feps[NPH] = 1e-4f; md[NPH] = 1; NPH++;                   // final

  const double L2E  = 1.4426950408889634;
  const double LN2d = 0.6931471805599453;

  float inv0ce = (float)(L2E / (double)feps[0]);
  ws_sort<<<2, 1024, 0, stream>>>(x, y, sidx);
  ws_setup<<<(NPTS + 255) / 256, 256, 0, stream>>>(x, y, sidx, xp, yp, bpA, bpB);
  ws_bbox<<<2, 512, 0, stream>>>(xp, yp, bbox, cent, ccA, inv0ce);
  ws_dmin<<<512, 512, 0, stream>>>(bbox, dmin);

  for (int p = 0; p < NPH; ++p) {
    float epsf = feps[p];
    float ce = (float)(L2E / (double)epsf);
    float eps_ln2 = (float)((double)epsf * LN2d);
    float inv_next_ce = 0.f;
    float rho_next = 0.f;
    if (p < NPH - 1) {
      inv_next_ce = (float)(L2E / (double)feps[p+1]);
      rho_next = (float)((double)epsf / (double)feps[p+1]);
    }
    int kind = (p == 0) ? 0 : ((p == NPH - 1) ? 2 : 1);
    const unsigned short* bpS = (p & 1) ? bpB : bpA;
    unsigned short*       bpD_ = (p & 1) ? bpA : bpB;
    const float4* ccS = (p & 1) ? ccB : ccA;
    float4*       ccD = (p & 1) ? ccA : ccB;
    const float*  hmS = (p & 1) ? hmB : hmA;
    float*        hmD = (p & 1) ? hmA : hmB;
    ws_softmin<<<512, 1024, 0, stream>>>(xp, yp, apack, bpS, bpD_, ccS, ccD,
                                         dmin, hmS, hmD, Mw, cent, P, Tfin,
                                         ce, eps_ln2, inv_next_ce, rho_next,
                                         kind, md[p]);
  }

  ws_reduce<<<1, 256, 0, stream>>>(Tfin, out);
}

// Round 9
// 897.253 us; speedup vs baseline: 2.4347x; 1.0318x over previous
//
#include <hip/hip_runtime.h>
#include <math.h>

#define NPTS 8192
#define LGAB2 (-13.0f)   // log2(1/8192)
#define NWAVE 16         // waves per block (1024 threads)
#define MARGIN 20.0f     // chunk skip margin vs M_est (exponent units, base 2)

typedef __attribute__((ext_vector_type(2))) float f2;
typedef __attribute__((ext_vector_type(4))) float f32x4;
typedef __attribute__((ext_vector_type(8))) short bf8;          // 8 bf16 (4 VGPR)
typedef __attribute__((ext_vector_type(8))) unsigned short us8;

__device__ __forceinline__ float fexp2(float x){
#if __has_builtin(__builtin_amdgcn_exp2f)
  return __builtin_amdgcn_exp2f(x);
#else
  return exp2f(x);
#endif
}
__device__ __forceinline__ f2 ffma2(f2 a, f2 b, f2 c){
  return __builtin_elementwise_fma(a, b, c);
}
__device__ __forceinline__ f2 fmax2(f2 a, f2 b){
  return __builtin_elementwise_max(a, b);
}
__device__ __forceinline__ f2 splat2(float v){ f2 r; r.x = v; r.y = v; return r; }

// bf16 round-to-nearest-even helpers + 3-way split (xh+xm+xl, residual 2^-27)
__device__ __forceinline__ unsigned short f2bf(float f){
  unsigned u = __builtin_bit_cast(unsigned, f);
  unsigned r = u + 0x7FFFu + ((u >> 16) & 1u);
  return (unsigned short)(r >> 16);
}
__device__ __forceinline__ float bf2f(unsigned short s){
  unsigned u = ((unsigned)s) << 16;
  return __builtin_bit_cast(float, u);
}
__device__ __forceinline__ void split3(float v, unsigned short& a,
                                       unsigned short& b, unsigned short& c){
  a = f2bf(v); float r = v - bf2f(a);
  b = f2bf(r); r -= bf2f(b);
  c = f2bf(r);
}

// sum over each 16-lane DPP row; lane 15 (mod 16) holds the row total
__device__ __forceinline__ float dpp_sum16(float x){
  int v = __builtin_bit_cast(int, x);
#define DPP_STEP(ctrl) { \
    int o = __builtin_amdgcn_update_dpp(0, v, ctrl, 0xF, 0xF, true); \
    float f = __builtin_bit_cast(float, v) + __builtin_bit_cast(float, o); \
    v = __builtin_bit_cast(int, f); }
  DPP_STEP(0x111)  // row_shr:1
  DPP_STEP(0x112)  // row_shr:2
  DPP_STEP(0x114)  // row_shr:4
  DPP_STEP(0x118)  // row_shr:8
#undef DPP_STEP
  return __builtin_bit_cast(float, v);
}

// ---------------- counting sort by 12-bit Morton key (16^3 cells) ------------
__global__ __launch_bounds__(1024) void ws_sort(
    const float* __restrict__ x, const float* __restrict__ y,
    unsigned* __restrict__ sidx)
{
  __shared__ unsigned hist[4096];
  __shared__ unsigned wtot[16];
  const float* p = blockIdx.x ? y : x;
  int tid = threadIdx.x;
  for (int i = tid; i < 4096; i += 1024) hist[i] = 0;
  __syncthreads();
  unsigned key[8];
  for (int t = 0; t < 8; ++t) {
    int i = tid + (t << 10);
    unsigned q0 = (unsigned)fminf(fmaxf(p[3*i  ] * 16.f, 0.f), 15.f);
    unsigned q1 = (unsigned)fminf(fmaxf(p[3*i+1] * 16.f, 0.f), 15.f);
    unsigned q2 = (unsigned)fminf(fmaxf(p[3*i+2] * 16.f, 0.f), 15.f);
    unsigned k = 0;
    #pragma unroll
    for (int bb = 0; bb < 4; ++bb)
      k |= (((q0 >> bb) & 1u) << (3*bb)) | (((q1 >> bb) & 1u) << (3*bb+1))
         | (((q2 >> bb) & 1u) << (3*bb+2));
    key[t] = k;
    atomicAdd(&hist[k], 1u);
  }
  __syncthreads();
  unsigned c0 = hist[4*tid], c1 = hist[4*tid+1], c2 = hist[4*tid+2], c3 = hist[4*tid+3];
  unsigned tsum = c0 + c1 + c2 + c3;
  int lane = tid & 63, wv = tid >> 6;
  unsigned inc = tsum;
  for (int d = 1; d < 64; d <<= 1) {
    unsigned o = __shfl_up(inc, d);
    if (lane >= d) inc += o;
  }
  if (lane == 63) wtot[wv] = inc;
  __syncthreads();
  unsigned woff = 0;
  for (int k = 0; k < wv; ++k) woff += wtot[k];
  unsigned base = woff + inc - tsum;
  hist[4*tid] = base; hist[4*tid+1] = base + c0;
  hist[4*tid+2] = base + c0 + c1; hist[4*tid+3] = base + c0 + c1 + c2;
  __syncthreads();
  for (int t = 0; t < 8; ++t) {
    int i = tid + (t << 10);
    unsigned pos = atomicAdd(&hist[key[t]], 1u);
    sidx[blockIdx.x * NPTS + pos] = i;
  }
}

// ---------------- B-pack static writer ----------------
// B-pack layout (shorts): [slot][ct(512)][g(4)*128][c(16)*8][j(8)]
// k-slot table p=g*8+j (A-side . B-side):
//  p0-2 xh_d.yh_d  p3-5 xm_d.yh_d  p6-8 xl_d.yh_d  p9-11 xh_d.ym_d
//  p12-14 xm_d.ym_d  p15-17 xh_d.yl_d  p18-20 1.h_split  p21-23 c_split.1
//  p24-31 zero. Any consistent A/B slot convention is valid (HW k-map is
//  symmetric between A and B); C layout col=lane&15,row=(lane>>4)*4+reg.
__device__ __forceinline__ void wbs(unsigned short* bp, int slot, int t,
    unsigned short h0, unsigned short h1, unsigned short h2,
    unsigned short m0, unsigned short m1, unsigned short m2,
    unsigned short l0, unsigned short l1, unsigned short l2)
{
  const unsigned short ONE = 0x3F80;
  size_t base = ((size_t)(slot*512 + (t >> 4))) * 512 + (size_t)(t & 15) * 8;
  us8 g0v = {h0,h1,h2,h0,h1,h2,h0,h1};
  us8 g1v = {h2,m0,m1,m2,m0,m1,m2,l0};
  us8 g2v = {l1,l2,0,0,0,ONE,ONE,ONE};   // h slots (j2..4) filled per phase
  us8 g3v = {0,0,0,0,0,0,0,0};
  *(us8*)(bp + base)        = g0v;
  *(us8*)(bp + base + 128)  = g1v;
  *(us8*)(bp + base + 256)  = g2v;
  *(us8*)(bp + base + 384)  = g3v;
}

__global__ __launch_bounds__(256) void ws_setup(
    const float* __restrict__ x, const float* __restrict__ y,
    const unsigned* __restrict__ sidx,
    float4* __restrict__ xp, float4* __restrict__ yp,
    unsigned short* __restrict__ bpA, unsigned short* __restrict__ bpB)
{
  int t = blockIdx.x * 256 + threadIdx.x;
  if (t >= NPTS) return;
  int ox = sidx[t], oy = sidx[NPTS + t];
  float x0 = x[3*ox], x1 = x[3*ox+1], x2 = x[3*ox+2];
  float xs = x0*x0 + x1*x1 + x2*x2;
  float y0 = y[3*oy], y1 = y[3*oy+1], y2 = y[3*oy+2];
  float ys = y0*y0 + y1*y1 + y2*y2;
  xp[t] = make_float4(x0,x1,x2,xs);
  yp[t] = make_float4(y0,y1,y2,ys);
  unsigned short a0,a1,a2,b0,b1,b2,c0,c1,c2;
  // x set -> columns of slots 1,2
  split3(x0,a0,b0,c0); split3(x1,a1,b1,c1); split3(x2,a2,b2,c2);
  wbs(bpA,1,t,a0,a1,a2,b0,b1,b2,c0,c1,c2);
  wbs(bpA,2,t,a0,a1,a2,b0,b1,b2,c0,c1,c2);
  wbs(bpB,1,t,a0,a1,a2,b0,b1,b2,c0,c1,c2);
  wbs(bpB,2,t,a0,a1,a2,b0,b1,b2,c0,c1,c2);
  // y set -> columns of slots 0,3
  split3(y0,a0,b0,c0); split3(y1,a1,b1,c1); split3(y2,a2,b2,c2);
  wbs(bpA,0,t,a0,a1,a2,b0,b1,b2,c0,c1,c2);
  wbs(bpA,3,t,a0,a1,a2,b0,b1,b2,c0,c1,c2);
  wbs(bpB,0,t,a0,a1,a2,b0,b1,b2,c0,c1,c2);
  wbs(bpB,3,t,a0,a1,a2,b0,b1,b2,c0,c1,c2);
}

// Per-16-pt cluster: bbox, centroid, and initial coarse pack (duals = 0).
__global__ __launch_bounds__(512) void ws_bbox(
    const float4* __restrict__ xp, const float4* __restrict__ yp,
    float4* __restrict__ bbox, float4* __restrict__ cent,
    float4* __restrict__ cc0, float inv0ce)
{
  int c = threadIdx.x;           // 0..511
  int set = blockIdx.x;
  const float4* pp = set ? yp : xp;
  float lx = 1e30f, ly = 1e30f, lz = 1e30f;
  float hxx = -1e30f, hyy = -1e30f, hzz = -1e30f;
  float sx = 0.f, sy = 0.f, sz = 0.f, hm = -3.0e38f;
  float hv[16];
  for (int k = 0; k < 16; ++k) {
    float4 v = pp[c*16+k];
    lx = fminf(lx, v.x); ly = fminf(ly, v.y); lz = fminf(lz, v.z);
    hxx = fmaxf(hxx, v.x); hyy = fmaxf(hyy, v.y); hzz = fmaxf(hzz, v.z);
    sx += v.x; sy += v.y; sz += v.z;
    float h = LGAB2 - 0.5f * v.w * inv0ce;
    hv[k] = h; hm = fmaxf(hm, h);
  }
  float se = 0.f;
  for (int k = 0; k < 16; ++k) se += fexp2(hv[k] - hm);
  float H = hm + log2f(se);
  bbox[(set*512+c)*2+0] = make_float4(lx, ly, lz, 0.f);
  bbox[(set*512+c)*2+1] = make_float4(hxx, hyy, hzz, 0.f);
  float cx = sx * 0.0625f, cy = sy * 0.0625f, cz = sz * 0.0625f;
  cent[set*512+c] = make_float4(cx, cy, cz, 0.f);
  int s1 = set ? 0 : 1, s2 = set ? 3 : 2;   // slots using this set as columns
  int p = c >> 1, sub = c & 1;
  float* a = (float*)(cc0 + (size_t)s1 * 512);
  a[p*8+sub] = cx; a[p*8+2+sub] = cy; a[p*8+4+sub] = cz; a[p*8+6+sub] = H;
  float* bq = (float*)(cc0 + (size_t)s2 * 512);
  bq[p*8+sub] = cx; bq[p*8+2+sub] = cy; bq[p*8+4+sub] = cz; bq[p*8+6+sub] = H;
}

// dmin^2 at 16-ROW-GROUP granularity.
__global__ __launch_bounds__(512) void ws_dmin(
    const float4* __restrict__ bbox, float* __restrict__ dmin)
{
  int b = blockIdx.x;
  int s = b >> 7, rb = b & 127;
  int c = threadIdx.x;
  int rset = (s == 0 || s == 2) ? 0 : 1;
  int cset = (s == 0 || s == 3) ? 1 : 0;
  float4 bl = bbox[(cset*512 + c)*2], bh = bbox[(cset*512 + c)*2+1];
  #pragma unroll
  for (int g = 0; g < 4; ++g) {
    float4 l = bbox[(rset*512 + 4*rb + g)*2];
    float4 h = bbox[(rset*512 + 4*rb + g)*2+1];
    float dx = fmaxf(0.f, fmaxf(l.x - bh.x, bl.x - h.x));
    float dy = fmaxf(0.f, fmaxf(l.y - bh.y, bl.y - h.y));
    float dz = fmaxf(0.f, fmaxf(l.z - bh.z, bl.z - h.z));
    dmin[(((size_t)s*512 + 4*rb + g) << 9) + c] = dx*dx + dy*dy + dz*dz;
  }
}

// One phase.
// mode 1: fine single pass via MFMA (R4-certified numerics and structure —
//   the session's best: 897 us, absmax 1.525879e-05). u = ce*x.y + h_j +
//   (hx - Mest) per 16x16 tile via mfma_f32_16x16x32_bf16 (bf16 triple-split
//   operands); VALU does exp2 + accumulate only. Skip at (16-col x 16-row)
//   granularity from hmS/dmin. R5-R8 established this loop's 48 us/full-scan
//   is a structural floor: spill-free pipelining (R7), batched counted-vmcnt
//   loads (R8) are neutral-to-negative; regime is trans-pipe/convoy-bound,
//   and the 1-ulp accuracy budget freezes term set, order, schedule, sort.
// mode 2: coarse exact two-pass over 512 centroid-columns (eps > 0.15 regime).
// kind: 0 = assign (init), 1 = 0.5*(P+T) average, 2 = final (write Tfin)
__global__ __launch_bounds__(1024, 4) void ws_softmin(
    const float4* __restrict__ xp, const float4* __restrict__ yp,
    unsigned short* __restrict__ apack,
    const unsigned short* __restrict__ bpS, unsigned short* __restrict__ bpD,
    const float4* __restrict__ ccS, float4* __restrict__ ccD,
    const float* __restrict__ dmin, const float* __restrict__ hmS,
    float* __restrict__ hmD, float* __restrict__ Mw,
    const float4* __restrict__ cent,
    float* __restrict__ P, float* __restrict__ Tfin,
    float ce, float eps_ln2, float inv_next_ce, float rho_next, int kind, int mode)
{
  int b = blockIdx.x;
  int s = b >> 7;
  int rb = b & 127;
  int rowbase = rb << 6;
  int tid = threadIdx.x;
  int lane = tid & 63;
  int w = __builtin_amdgcn_readfirstlane(tid >> 6);

  int rset = (s == 0 || s == 2) ? 0 : 1;
  const float4* rp = rset ? yp : xp;
  float4 rv = rp[rowbase + lane];
  float hx = -0.5f * rv.w * ce;
  int row = rowbase + lane;

  __shared__ float lm[NWAVE][64];
  __shared__ float lss[NWAVE][64];
  float myMest = 0.f;

  if (mode == 2) {
    // ---- coarse exact two-pass: 512 centroid-cols, 32 per wave ----
    float a0 = rv.x * ce, a1 = rv.y * ce, a2 = rv.z * ce;
    f2 A0 = splat2(a0), A1 = splat2(a1), A2 = splat2(a2);
    const float4* pwc = ccS + (size_t)s*512 + (w << 5);
    f2 mA = {-3.0e38f, -3.0e38f}, mB = mA;
    #pragma unroll
    for (int pb = 0; pb < 16; pb += 2) {
      float4 P0 = pwc[2*pb+0], Q0 = pwc[2*pb+1];
      float4 P1 = pwc[2*pb+2], Q1 = pwc[2*pb+3];
      f2 X0={P0.x,P0.y}, Y0={P0.z,P0.w}, Z0={Q0.x,Q0.y}, W0={Q0.z,Q0.w};
      f2 X1={P1.x,P1.y}, Y1={P1.z,P1.w}, Z1={Q1.x,Q1.y}, W1={Q1.z,Q1.w};
      f2 t0 = ffma2(A2, Z0, W0); t0 = ffma2(A1, Y0, t0); t0 = ffma2(A0, X0, t0);
      f2 t1 = ffma2(A2, Z1, W1); t1 = ffma2(A1, Y1, t1); t1 = ffma2(A0, X1, t1);
      mA = fmax2(mA, t0); mB = fmax2(mB, t1);
    }
    f2 mAB = fmax2(mA, mB);
    float m = fmaxf(mAB.x, mAB.y);
    f2 M2 = {m, m};
    f2 sA = {0.f,0.f}, sB = {0.f,0.f};
    #pragma unroll
    for (int pb = 0; pb < 16; pb += 2) {
      float4 P0 = pwc[2*pb+0], Q0 = pwc[2*pb+1];
      float4 P1 = pwc[2*pb+2], Q1 = pwc[2*pb+3];
      f2 X0={P0.x,P0.y}, Y0={P0.z,P0.w}, Z0={Q0.x,Q0.y}, W0={Q0.z,Q0.w};
      f2 X1={P1.x,P1.y}, Y1={P1.z,P1.w}, Z1={Q1.x,Q1.y}, W1={Q1.z,Q1.w};
      f2 u0 = ffma2(A2, Z0, W0 - M2); u0 = ffma2(A1, Y0, u0); u0 = ffma2(A0, X0, u0);
      f2 u1 = ffma2(A2, Z1, W1 - M2); u1 = ffma2(A1, Y1, u1); u1 = ffma2(A0, X1, u1);
      f2 e0, e1;
      e0.x = fexp2(u0.x); e0.y = fexp2(u0.y);
      e1.x = fexp2(u1.x); e1.y = fexp2(u1.y);
      sA += e0; sB += e1;
    }
    f2 sAB = sA + sB;
    lm[w][lane] = m;
    lss[w][lane] = sAB.x + sAB.y;
  } else {
    // ---- fine single pass, MFMA ----
    float MestL = Mw[(size_t)s * NPTS + rowbase + lane];
    myMest = MestL;
    // per-16-row-group MIN of Mest (exists-row skip semantics)
    float gmn = MestL;
    #pragma unroll
    for (int d = 8; d >= 1; d >>= 1) gmn = fminf(gmn, __shfl_xor(gmn, d));
    float thr0 = __shfl(gmn,  0) - MARGIN;
    float thr1 = __shfl(gmn, 16) - MARGIN;
    float thr2 = __shfl(gmn, 32) - MARGIN;
    float thr3 = __shfl(gmn, 48) - MARGIN;
    // masks: bit i of m[rt] -> ct = w + 16*i live for row-tile rt
    int il = lane & 31;
    int ctl = w + (il << 4);
    float hmv = hmS[s*512 + ctl];
    unsigned m0x, m1x, m2x, m3x;
    {
      float dm0 = dmin[(((size_t)s*512 + 4*rb + 0) << 9) + ctl];
      float dm1 = dmin[(((size_t)s*512 + 4*rb + 1) << 9) + ctl];
      float dm2 = dmin[(((size_t)s*512 + 4*rb + 2) << 9) + ctl];
      float dm3 = dmin[(((size_t)s*512 + 4*rb + 3) << 9) + ctl];
      bool lo = (lane < 32);
      m0x = (unsigned)__ballot(lo && (hmv - 0.5f*ce*dm0 > thr0));
      m1x = (unsigned)__ballot(lo && (hmv - 0.5f*ce*dm1 > thr1));
      m2x = (unsigned)__ballot(lo && (hmv - 0.5f*ce*dm2 > thr2));
      m3x = (unsigned)__ballot(lo && (hmv - 0.5f*ce*dm3 > thr3));
      if (m0x == 0u) m0x = 0xFFFFFFFFu;
      if (m1x == 0u) m1x = 0xFFFFFFFFu;
      if (m2x == 0u) m2x = 0xFFFFFFFFu;
      if (m3x == 0u) m3x = 0xFFFFFFFFu;
    }
    unsigned msk[4] = {m0x, m1x, m2x, m3x};
    unsigned any = m0x | m1x | m2x | m3x;
    // A fragments: 4 row-tiles
    const unsigned short* apb = apack + (((size_t)s * NPTS + rowbase) << 5);
    bf8 af[4];
    #pragma unroll
    for (int rt = 0; rt < 4; ++rt)
      af[rt] = *(const bf8*)(apb + (((rt*16) + (lane & 15)) << 5) + ((lane >> 4) << 3));
    f32x4 acc[4];
    #pragma unroll
    for (int rt = 0; rt < 4; ++rt) acc[rt] = (f32x4){0.f,0.f,0.f,0.f};
    const f32x4 kZero = {0.f,0.f,0.f,0.f};
    const unsigned short* bpb = bpS + (((size_t)s) << 18);
    int goff = ((lane >> 4) << 7) + ((lane & 15) << 3);
    unsigned rem = any;
    int ic = __builtin_ctz(rem); rem &= rem - 1u;
    bf8 bc = *(const bf8*)(bpb + (size_t)(w + (ic << 4)) * 512 + goff);
    for (;;) {
      int in = -1; bf8 bn;
      if (rem) {                           // issue next ct's load EARLY
        in = __builtin_ctz(rem); rem &= rem - 1u;
        bn = *(const bf8*)(bpb + (size_t)(w + (in << 4)) * 512 + goff);
      }
      #pragma unroll
      for (int rt = 0; rt < 4; ++rt) {
        if ((msk[rt] >> ic) & 1u) {
          f32x4 d = __builtin_amdgcn_mfma_f32_16x16x32_bf16(af[rt], bc, kZero, 0, 0, 0);
          f32x4 e;
          e.x = fexp2(d.x); e.y = fexp2(d.y); e.z = fexp2(d.z); e.w = fexp2(d.w);
          acc[rt] += e;
        }
      }
      if (in < 0) break;
      ic = in; bc = bn;
    }
    // reduce: sum over the 16 lanes of each group (cols) -> per-row totals
    #pragma unroll
    for (int rt = 0; rt < 4; ++rt) {
      #pragma unroll
      for (int q = 0; q < 4; ++q) {
        float v = dpp_sum16(acc[rt][q]);
        if ((lane & 15) == 15)
          lss[w][rt*16 + ((lane >> 4) << 2) + q] = v;
      }
    }
  }
  __syncthreads();

  if (tid < 64) {
    float L;
    if (mode == 1) {
      float S = 0.f;
      #pragma unroll
      for (int k = 0; k < NWAVE; ++k) S += lss[k][lane];
      S = fmaxf(S, 1e-30f);
      L = myMest + log2f(S);
    } else {
      float M = lm[0][lane];
      #pragma unroll
      for (int k = 1; k < NWAVE; ++k) M = fmaxf(M, lm[k][lane]);
      float S = 0.f;
      #pragma unroll
      for (int k = 0; k < NWAVE; ++k) S += lss[k][lane] * fexp2(lm[k][lane] - M);
      L = hx + M + log2f(S);
    }
    float T = -eps_ln2 * L;
    if (kind == 2) {
      Tfin[s * NPTS + row] = T;
    } else {
      float* Pr = P + s * NPTS;
      float Pn = (kind == 0) ? T : 0.5f * (Pr[row] + T);
      Pr[row] = Pn;
      int dst = (s == 0) ? 1 : ((s == 1) ? 0 : s);
      // h for dst-slot columns (3-way split into B-pack h slots)
      float hy = LGAB2 + (Pn - 0.5f * rv.w) * inv_next_ce;
      {
        unsigned short hh, hmm, hl;
        split3(hy, hh, hmm, hl);
        size_t hb = ((size_t)(dst*512 + (row >> 4))) * 512 + 256 + (size_t)(row & 15) * 8;
        bpD[hb + 2] = hh; bpD[hb + 3] = hmm; bpD[hb + 4] = hl;
      }
      // A-pack row record for own slot's next phase + Mw (= next Mest)
      float Mn = fmaf(L - LGAB2, rho_next, LGAB2);
      Mw[(size_t)s * NPTS + row] = Mn;
      {
        float cen = inv_next_ce;
        unsigned short a0h,a0m,a0l,a1h,a1m,a1l,a2h,a2m,a2l,ch,cm,cl;
        split3(rv.x * cen, a0h, a0m, a0l);
        split3(rv.y * cen, a1h, a1m, a1l);
        split3(rv.z * cen, a2h, a2m, a2l);
        float cr = (-0.5f * rv.w * cen) - Mn;
        split3(cr, ch, cm, cl);
        const unsigned short ONE = 0x3F80;
        us8 A0 = {a0h,a1h,a2h,a0m,a1m,a2m,a0l,a1l};
        us8 A1 = {a2l,a0h,a1h,a2h,a0m,a1m,a2m,a0h};
        us8 A2 = {a1h,a2h,ONE,ONE,ONE,ch,cm,cl};
        us8 A3 = {0,0,0,0,0,0,0,0};
        unsigned short* ap = apack + (((size_t)s * NPTS + row) << 5);
        *(us8*)(ap)      = A0;
        *(us8*)(ap + 8)  = A1;
        *(us8*)(ap + 16) = A2;
        *(us8*)(ap + 24) = A3;
      }
      // Skip-bound table: MUST be LGAB2 + Pn*ce (R14 errata: max(h_j) is NOT
      // a valid bound — the -0.5|y|^2 cancels against the x.y cross term).
      float hN = fmaf(Pn, inv_next_ce, LGAB2);
      #pragma unroll
      for (int d = 8; d >= 1; d >>= 1) hN = fmaxf(hN, __shfl_xor(hN, d));
      if ((lane & 15) == 0) hmD[dst*512 + 4*rb + (lane >> 4)] = hN;
      // coarse pack for next phase: cluster LSE of hy over 16-lane group
      float mh = hy;
      #pragma unroll
      for (int d = 8; d >= 1; d >>= 1) mh = fmaxf(mh, __shfl_xor(mh, d));
      float se = fexp2(hy - mh);
      #pragma unroll
      for (int d = 8; d >= 1; d >>= 1) se += __shfl_xor(se, d);
      float Hcs = mh + log2f(se);
      if ((lane & 15) == 0) {
        int gc = 4*rb + (lane >> 4);
        float4 cv = cent[rset*512 + gc];
        float* cc2 = (float*)(ccD + (size_t)dst * 512);
        int p2 = gc >> 1, sub2 = gc & 1;
        cc2[p2*8+sub2]   = cv.x;
        cc2[p2*8+2+sub2] = cv.y;
        cc2[p2*8+4+sub2] = cv.z;
        cc2[p2*8+6+sub2] = Hcs;
      }
    }
  }
}

// loss = mean(f_fin - p_fin) + mean(g_fin - q_fin), fp64 accumulation
__global__ __launch_bounds__(256) void ws_reduce(
    const float* __restrict__ Tfin, float* __restrict__ out)
{
  int tid = threadIdx.x;
  double acc = 0.0;
  for (int i = tid; i < NPTS; i += 256) {
    acc += (double)Tfin[0*NPTS+i] - (double)Tfin[2*NPTS+i]
         + (double)Tfin[1*NPTS+i] - (double)Tfin[3*NPTS+i];
  }
  __shared__ double sd[256];
  sd[tid] = acc; __syncthreads();
  for (int k = 128; k > 0; k >>= 1) {
    if (tid < k) sd[tid] += sd[tid + k];
    __syncthreads();
  }
  if (tid == 0) out[0] = (float)(sd[0] / (double)NPTS);
}

extern "C" void kernel_launch(void* const* d_in, const int* in_sizes, int n_in,
                              void* d_out, int out_size, void* d_ws, size_t ws_size,
                              hipStream_t stream)
{
  const float* x = (const float*)d_in[0];
  const float* y = (const float*)d_in[1];
  float* out = (float*)d_out;

  char* wsp = (char*)d_ws;
  float4*   xp   = (float4*)wsp;   wsp += (size_t)NPTS * 16;
  float4*   yp   = (float4*)wsp;   wsp += (size_t)NPTS * 16;
  unsigned short* apack = (unsigned short*)wsp; wsp += (size_t)4 * NPTS * 64;  // 2 MB
  unsigned short* bpA   = (unsigned short*)wsp; wsp += (size_t)4 * 512 * 1024; // 2 MB
  unsigned short* bpB   = (unsigned short*)wsp; wsp += (size_t)4 * 512 * 1024; // 2 MB
  float4*   ccA  = (float4*)wsp;   wsp += (size_t)4 * 512 * 16;
  float4*   ccB  = (float4*)wsp;   wsp += (size_t)4 * 512 * 16;
  float*    P    = (float*)wsp;    wsp += (size_t)4 * NPTS * 4;
  float*    Tfin = (float*)wsp;    wsp += (size_t)4 * NPTS * 4;
  unsigned* sidx = (unsigned*)wsp; wsp += (size_t)2 * NPTS * 4;
  float*    Mw   = (float*)wsp;    wsp += (size_t)4 * NPTS * 4;
  float*    hmA  = (float*)wsp;    wsp += (size_t)4 * 512 * 4;
  float*    hmB  = (float*)wsp;    wsp += (size_t)4 * 512 * 4;
  float4*   bbox = (float4*)wsp;   wsp += (size_t)2 * 512 * 2 * 16;
  float4*   cent = (float4*)wsp;   wsp += (size_t)2 * 512 * 16;
  float*    dmin = (float*)wsp;    wsp += (size_t)4 * 512 * 512 * 4;  // 4 MB

  // geomloss epsilon schedule (f64, exactly as Python builds it)
  double epss[64]; int n = 0;
  double e = 4.0;                       // DIAMETER**P
  const double r = 0.9 * 0.9;          // SCALING**P
  const double target = 0.01 * 0.01;   // BLUR**P
  while (e > target && n < 60) { epss[n++] = e; e *= r; }   // n == 51

  // Phase plan (identical to the 1128 µs baseline — no error headroom for
  // schedule approximations): eps > 0.15 -> coarse512 (mode 2) stride-3;
  // 0.15 >= eps > 0.0025 -> fine stride-2; eps <= 0.0025 -> fine dense.
  // Final extrapolation at eps_final, fine.
  float feps[80]; int md[80]; int NPH = 0;
  feps[NPH] = (float)epss[0]; md[NPH] = 2; NPH++;          // init (coarse)
  {
    int k = 0;
    while (k < n) {
      int coarse = (epss[k] > 0.15);
      feps[NPH] = (float)epss[k]; md[NPH] = coarse ? 2 : 1; NPH++;
      k += coarse ? 3 : ((epss[k] > 0.0025) ? 2 : 1);
    }
  }
  feps[NPH] = 1e-4f; md[NPH] = 1; NPH++;                   // final

  const double L2E  = 1.4426950408889634;
  const double LN2d = 0.6931471805599453;

  float inv0ce = (float)(L2E / (double)feps[0]);
  ws_sort<<<2, 1024, 0, stream>>>(x, y, sidx);
  ws_setup<<<(NPTS + 255) / 256, 256, 0, stream>>>(x, y, sidx, xp, yp, bpA, bpB);
  ws_bbox<<<2, 512, 0, stream>>>(xp, yp, bbox, cent, ccA, inv0ce);
  ws_dmin<<<512, 512, 0, stream>>>(bbox, dmin);

  for (int p = 0; p < NPH; ++p) {
    float epsf = feps[p];
    float ce = (float)(L2E / (double)epsf);
    float eps_ln2 = (float)((double)epsf * LN2d);
    float inv_next_ce = 0.f;
    float rho_next = 0.f;
    if (p < NPH - 1) {
      inv_next_ce = (float)(L2E / (double)feps[p+1]);
      rho_next = (float)((double)epsf / (double)feps[p+1]);
    }
    int kind = (p == 0) ? 0 : ((p == NPH - 1) ? 2 : 1);
    const unsigned short* bpS = (p & 1) ? bpB : bpA;
    unsigned short*       bpD_ = (p & 1) ? bpA : bpB;
    const float4* ccS = (p & 1) ? ccB : ccA;
    float4*       ccD = (p & 1) ? ccA : ccB;
    const float*  hmS = (p & 1) ? hmB : hmA;
    float*        hmD = (p & 1) ? hmA : hmB;
    ws_softmin<<<512, 1024, 0, stream>>>(xp, yp, apack, bpS, bpD_, ccS, ccD,
                                         dmin, hmS, hmD, Mw, cent, P, Tfin,
                                         ce, eps_ln2, inv_next_ce, rho_next,
                                         kind, md[p]);
  }

  ws_reduce<<<1, 256, 0, stream>>>(Tfin, out);
}